// Round 2
// baseline (3156.561 us; speedup 1.0000x reference)
//
#include <hip/hip_runtime.h>
#include <math.h>

typedef unsigned short u16;
typedef unsigned int u32;
typedef float f32x4 __attribute__((ext_vector_type(4)));
typedef __bf16 bf16x8 __attribute__((ext_vector_type(8)));

#define LAYERS 6
#define NHEADS 12
#define INDIM 128
#define HDIM 768
#define OUTC 10
#define BDIM 8
#define FFDIM 3072
#define BB 16
#define NNODE 448
#define SEQ 449
#define DHEAD 64
#define MROWS (BB*SEQ)      // 7184
#define MROWS0 (BB*NNODE)   // 7168
#define QKVW 2304

__device__ __forceinline__ u16 f2b(float f) {
  u32 u = __float_as_uint(f);
  u32 r = (u + 0x7fffu + ((u >> 16) & 1u)) >> 16;
  return (u16)r;
}
__device__ __forceinline__ float b2f(u16 h) {
  return __uint_as_float(((u32)h) << 16);
}

// fast exact-enough erf (A&S 7.1.26, |abs err| < 1.5e-7 — far below bf16 quantum)
__device__ __forceinline__ float fast_erf(float x) {
  float ax = fabsf(x);
  float t = __builtin_amdgcn_rcpf(1.0f + 0.3275911f * ax);
  float poly = t * (0.254829592f + t * (-0.284496736f + t * (1.421413741f +
               t * (-1.453152027f + t * 1.061405429f))));
  float er = 1.0f - poly * __expf(-ax * ax);
  return copysignf(er, x);
}

// direct global->LDS DMA, 16B per lane. LDS dest = wave-uniform base + lane*16.
__device__ __forceinline__ void gload16(const u16* g, u16* l) {
  __builtin_amdgcn_global_load_lds((const __attribute__((address_space(1))) void*)g,
                                   (__attribute__((address_space(3))) void*)l,
                                   16, 0, 0);
}

// ---------------- transpose + fp32->bf16 convert: in (K,N) -> out (N,K) ----------------
__device__ __forceinline__ void tile_transpose(const float* in, u16* out, int K, int N,
                                               float (*sm)[33]) {
  int n0 = blockIdx.x * 32, k0 = blockIdx.y * 32;
  int tx = threadIdx.x & 31, ty = threadIdx.x >> 5;
#pragma unroll
  for (int r = 0; r < 4; r++)
    sm[ty + 8*r][tx] = in[(size_t)(k0 + ty + 8*r) * N + n0 + tx];
  __syncthreads();
#pragma unroll
  for (int r = 0; r < 4; r++)
    out[(size_t)(n0 + ty + 8*r) * K + k0 + tx] = f2b(sm[tx][ty + 8*r]);
}

__global__ __launch_bounds__(256) void k_transpose_b(const float* __restrict__ in,
                                                     u16* __restrict__ out, int K, int N) {
  __shared__ float sm[32][33];
  in  += (size_t)blockIdx.z * K * N;
  out += (size_t)blockIdx.z * K * N;
  tile_transpose(in, out, K, N, sm);
}

__global__ __launch_bounds__(256) void k_transpose_qkv(const float* __restrict__ Wq,
    const float* __restrict__ Wk, const float* __restrict__ Wv, u16* __restrict__ out) {
  __shared__ float sm[32][33];
  int z = blockIdx.z; int l = z / 3, m = z - 3 * l;
  const float* in = (m == 0 ? Wq : (m == 1 ? Wk : Wv)) + (size_t)l * HDIM * HDIM;
  u16* o = out + (size_t)l * QKVW * HDIM + (size_t)m * HDIM * HDIM;
  tile_transpose(in, o, HDIM, HDIM, sm);
}

__global__ __launch_bounds__(256) void k_cvt(const float* __restrict__ in,
                                             u16* __restrict__ out, int n) {
  int i = blockIdx.x * 256 + threadIdx.x;
  if (i < n) out[i] = f2b(in[i]);
}

__global__ __launch_bounds__(256) void k_token(const float* __restrict__ gt, float* __restrict__ h) {
  int b = blockIdx.x;
  for (int d = threadIdx.x; d < HDIM; d += 256)
    h[((size_t)b * SEQ + NNODE) * HDIM + d] = gt[d];
}

// ---------------- LayerNorm: h fp32 row -> y bf16 row ----------------
__global__ __launch_bounds__(256) void k_ln(const float* __restrict__ h, const float* __restrict__ g,
                                            const float* __restrict__ bta, u16* __restrict__ y) {
  int row = blockIdx.x;
  const float* x = h + (size_t)row * HDIM;
  int t = threadIdx.x;
  float v0 = x[t], v1 = x[t + 256], v2 = x[t + 512];
  float s = v0 + v1 + v2;
  float q = v0*v0 + v1*v1 + v2*v2;
#pragma unroll
  for (int m = 32; m >= 1; m >>= 1) { s += __shfl_xor(s, m); q += __shfl_xor(q, m); }
  __shared__ float ss[4], qq[4];
  int w = t >> 6;
  if ((t & 63) == 0) { ss[w] = s; qq[w] = q; }
  __syncthreads();
  s = ss[0] + ss[1] + ss[2] + ss[3];
  q = qq[0] + qq[1] + qq[2] + qq[3];
  float mean = s * (1.0f / HDIM);
  float var = q * (1.0f / HDIM) - mean * mean;
  float rs = rsqrtf(var + 1e-5f);
  u16* yr = y + (size_t)row * HDIM;
  yr[t]       = f2b((v0 - mean) * rs * g[t]       + bta[t]);
  yr[t + 256] = f2b((v1 - mean) * rs * g[t + 256] + bta[t + 256]);
  yr[t + 512] = f2b((v2 - mean) * rs * g[t + 512] + bta[t + 512]);
}

// ---------------- bf16 MFMA GEMM: C(M,N) = A(M,K) * Bt(N,K)^T ----------------
// 2-phase double-buffered K-loop (T3 minimum schedule): issue next tile's
// global_load_lds right AFTER the barrier, then compute the current tile —
// the barrier's vmcnt(0) drain lands after a full compute phase has hidden
// the load latency. One barrier per K-step, x2 unrolled for static buffer
// indices (kiters is always even: 2/12/48).
// T2 both-sides chunk swizzle (chunk ^= row&7) on the GLOBAL source during
// staging and on the ds_read_b128 address -> conflict-free with linear LDS.
// 1D grid with XCD-affinity swizzle: blocks lin%8==x land on XCD x.
// mode 0: enc  -> hbuf fp32 with (b,448-node)->(b,449-row) remap, +bias0
// mode 1: qkv  -> obf bf16 stride 2304, bias = concat(bq,bk,bv)
// mode 2: Wo   -> hbuf += acc + bias0
// mode 3: ffn1 -> obf bf16 stride 3072, fast-exact GELU(acc+bias0)
// mode 4: ffn2 -> hbuf += acc + bias0
__global__ __launch_bounds__(256) void k_gemm(const u16* __restrict__ A, const u16* __restrict__ Bt,
    int M, int Kd, int nbn, int mode,
    const float* __restrict__ bias0, const float* __restrict__ bias1, const float* __restrict__ bias2,
    float* __restrict__ hbuf, u16* __restrict__ obf) {
  int lin = blockIdx.x;
  int grpsz = nbn * 8;
  int grp = lin / grpsz;
  int rem = lin - grp * grpsz;
  int bn = rem >> 3;
  int bm = grp * 8 + (rem & 7);
  if (bm * 128 >= M) return;

  __shared__ __align__(16) u16 As[2][128 * 64];
  __shared__ __align__(16) u16 Bs[2][128 * 64];
  int tid = threadIdx.x;
  int lane = tid & 63, wave = tid >> 6;
  int wm = wave >> 1, wn = wave & 1;
  int lh = lane & 15, quad = lane >> 4;

  f32x4 zero4 = {0.f, 0.f, 0.f, 0.f};
  f32x4 acc[4][4];
#pragma unroll
  for (int i = 0; i < 4; i++)
#pragma unroll
    for (int j = 0; j < 4; j++) acc[i][j] = zero4;

  // staging map: wave w, round r covers LDS rows [w*32+r*8, +8); lane l ->
  // row w*32+r*8+(l>>3), LDS chunk l&7, GLOBAL chunk (l&7)^(l>>3)  (row&7 == l>>3)
  int schunk = ((lane & 7) ^ (lane >> 3)) * 8;  // u16 units, 16B chunks
  const u16* pa[4];
  const u16* pb[4];
#pragma unroll
  for (int r = 0; r < 4; r++) {
    int ar = bm * 128 + wave * 32 + r * 8 + (lane >> 3);
    if (ar > M - 1) ar = M - 1;  // duplicate row; outputs masked at epilogue
    pa[r] = A + (size_t)ar * Kd + schunk;
    int br = bn * 128 + wave * 32 + r * 8 + (lane >> 3);  // N always multiple of 128
    pb[r] = Bt + (size_t)br * Kd + schunk;
  }
  int ldsb = wave * 2048;  // u16 idx: wave*4096 bytes

  auto stage = [&](int bufi) {
#pragma unroll
    for (int r = 0; r < 4; r++) {
      gload16(pa[r], &As[bufi][ldsb + r * 512]);
      gload16(pb[r], &Bs[bufi][ldsb + r * 512]);
      pa[r] += 64; pb[r] += 64;
    }
  };
  auto compute = [&](int bufi) {
#pragma unroll
    for (int ks = 0; ks < 2; ks++) {
      int cs = (((ks * 4 + quad) ^ (lh & 7)) * 8);  // read-side swizzle (row&7 == lh&7)
      bf16x8 af[4], bfr[4];
#pragma unroll
      for (int mt = 0; mt < 4; mt++)
        af[mt] = *(const bf16x8*)&As[bufi][(wm * 64 + mt * 16 + lh) * 64 + cs];
#pragma unroll
      for (int nt = 0; nt < 4; nt++)
        bfr[nt] = *(const bf16x8*)&Bs[bufi][(wn * 64 + nt * 16 + lh) * 64 + cs];
#pragma unroll
      for (int mt = 0; mt < 4; mt++)
#pragma unroll
        for (int nt = 0; nt < 4; nt++)
          acc[mt][nt] = __builtin_amdgcn_mfma_f32_16x16x32_bf16(af[mt], bfr[nt], acc[mt][nt], 0, 0, 0);
    }
  };

  int kiters = Kd >> 6;  // always even (2 / 12 / 48)
  stage(0);              // prologue: tile 0
  for (int kt = 0; kt < kiters; kt += 2) {
    __syncthreads();     // vmcnt(0) drain -> buf0 staged; prior reads of buf1 done
    stage(1);            // tile kt+1 (exists: kiters even)
    compute(0);          // hides tile kt+1's load latency
    __syncthreads();     // buf1 ready; prior reads of buf0 done
    if (kt + 2 < kiters) stage(0);  // tile kt+2
    compute(1);
  }

#pragma unroll
  for (int mt = 0; mt < 4; mt++) {
#pragma unroll
    for (int nt = 0; nt < 4; nt++) {
      f32x4 v = acc[mt][nt];
      int gc = bn * 128 + wn * 64 + nt * 16 + lh;
#pragma unroll
      for (int r = 0; r < 4; r++) {
        int gr = bm * 128 + wm * 64 + mt * 16 + quad * 4 + r;
        if (gr >= M) continue;
        float val = v[r];
        if (mode == 0) {
          int b = gr / NNODE, sNode = gr - b * NNODE;
          hbuf[((size_t)(b * SEQ + sNode)) * HDIM + gc] = val + bias0[gc];
        } else if (mode == 1) {
          float bias = (gc < 768) ? bias0[gc] : ((gc < 1536) ? bias1[gc - 768] : bias2[gc - 1536]);
          obf[(size_t)gr * QKVW + gc] = f2b(val + bias);
        } else if (mode == 3) {
          float tt = val + bias0[gc];
          float gg = 0.5f * tt * (1.0f + fast_erf(tt * 0.70710678f));
          obf[(size_t)gr * FFDIM + gc] = f2b(gg);
        } else {  // mode 2 / 4: residual accumulate
          size_t p = (size_t)gr * HDIM + gc;
          hbuf[p] += val + bias0[gc];
        }
      }
    }
  }
}

// ---------------- one-time compact pair bias: gb8 (B,S,S,8) bf16 ----------------
__global__ __launch_bounds__(256) void k_gb(const float* __restrict__ ab,
    const float* __restrict__ gvd, u16* __restrict__ gb8) {
  int blk = blockIdx.x;               // b*SEQ + q
  int b = blk / SEQ, q = blk - b * SEQ;
  float4 gv0 = *(const float4*)gvd;
  float4 gv1 = *(const float4*)(gvd + 4);
  for (int k = threadIdx.x; k < SEQ; k += 256) {
    float4 d0, d1;
    if (q < NNODE && k < NNODE) {
      const float* src = ab + (((size_t)b * NNODE + q) * NNODE + k) * BDIM;
      d0 = *(const float4*)src; d1 = *(const float4*)(src + 4);
    } else { d0 = gv0; d1 = gv1; }
    u16 o[8] = {f2b(d0.x), f2b(d0.y), f2b(d0.z), f2b(d0.w),
                f2b(d1.x), f2b(d1.y), f2b(d1.z), f2b(d1.w)};
    *(uint4*)&gb8[((size_t)blk * SEQ + k) * 8] = *(uint4*)o;
  }
}

// ---------------- flash attention with inline bias (gb8 . Wbias[:,head]) ----------------
// grid.x = qtile*12 + head (head fastest => 12 blocks share gb8 region in L2/L3)
// V tile (32 keys x 64 d) staged per k-chunk into LDS transposed (Vt[d][key],
// stride 40), global load issued early (T14) so latency hides under QK^T+softmax.
__global__ __launch_bounds__(256) void k_attn(const u16* __restrict__ qkv,
    const u16* __restrict__ gb8, const float* __restrict__ wbias,
    const float* __restrict__ bbv, u16* __restrict__ obf) {
  int head = blockIdx.x % 12, qt = blockIdx.x / 12;
  int b = blockIdx.y;
  int wave = threadIdx.x >> 6, lane = threadIdx.x & 63;
  int tid = threadIdx.x;
  int lh = lane & 15, quad = lane >> 4;
  int q0 = qt * 64 + wave * 16;

  float wcol[8];
#pragma unroll
  for (int d = 0; d < 8; d++) wcol[d] = wbias[d * 12 + head];
  float bb = bbv[head];

  __shared__ __align__(16) u16 P[4][16 * 32];
  __shared__ __align__(16) u16 Vt[64 * 40];  // [d][key] stride 40

  const u16* Qb = qkv + head * DHEAD;
  const u16* Kb = qkv + 768 + head * DHEAD;
  const u16* Vb = qkv + 1536 + head * DHEAD;

  int qr = q0 + lh; if (qr > NNODE) qr = NNODE;
  size_t qrow = ((size_t)b * SEQ + qr) * QKVW;
  bf16x8 aq0 = *(const bf16x8*)(Qb + qrow + quad * 8);
  bf16x8 aq1 = *(const bf16x8*)(Qb + qrow + 32 + quad * 8);

  // V staging map: thread t -> key kbase+(t>>3), dims (t&7)*8 .. +8 (coalesced 128B/row)
  int vkid = tid >> 3;
  int vd0 = (tid & 7) * 8;

  f32x4 zero4 = {0.f, 0.f, 0.f, 0.f};
  float mrun[4], lrun[4];
  f32x4 acc[4];
#pragma unroll
  for (int r = 0; r < 4; r++) { mrun[r] = -3.0e38f; lrun[r] = 0.f; }
#pragma unroll
  for (int nt = 0; nt < 4; nt++) acc[nt] = zero4;

  const u16* gb_b = gb8 + (size_t)b * SEQ * SEQ * 8;

  for (int kc = 0; kc < 15; kc++) {
    int kbase = kc * 32;
    int key0 = kbase + lh;      if (key0 > NNODE) key0 = NNODE;
    int key1 = kbase + 16 + lh; if (key1 > NNODE) key1 = NNODE;
    size_t kr0 = ((size_t)b * SEQ + key0) * QKVW;
    size_t kr1 = ((size_t)b * SEQ + key1) * QKVW;
    bf16x8 bk00 = *(const bf16x8*)(Kb + kr0 + quad * 8);
    bf16x8 bk01 = *(const bf16x8*)(Kb + kr0 + 32 + quad * 8);
    bf16x8 bk10 = *(const bf16x8*)(Kb + kr1 + quad * 8);
    bf16x8 bk11 = *(const bf16x8*)(Kb + kr1 + 32 + quad * 8);

    // issue V tile load early; consumed at the LDS write after the barrier
    int vkey = kbase + vkid; if (vkey > NNODE) vkey = NNODE;
    union { bf16x8 v; u16 u[8]; } vst;
    vst.v = *(const bf16x8*)(Vb + ((size_t)b * SEQ + vkey) * QKVW + vd0);

    f32x4 s0 = __builtin_amdgcn_mfma_f32_16x16x32_bf16(aq0, bk00, zero4, 0, 0, 0);
    s0 = __builtin_amdgcn_mfma_f32_16x16x32_bf16(aq1, bk01, s0, 0, 0, 0);
    f32x4 s1 = __builtin_amdgcn_mfma_f32_16x16x32_bf16(aq0, bk10, zero4, 0, 0, 0);
    s1 = __builtin_amdgcn_mfma_f32_16x16x32_bf16(aq1, bk11, s1, 0, 0, 0);

    int k0c = kbase + lh, k1c = kbase + 16 + lh;
    float sv0[4], sv1[4];
#pragma unroll
    for (int r = 0; r < 4; r++) {
      int qq = q0 + quad * 4 + r; if (qq > NNODE) qq = NNODE;
      const u16* gq = gb_b + (size_t)qq * SEQ * 8;
      union { bf16x8 v; u16 u[8]; } g0, g1;
      g0.v = *(const bf16x8*)(gq + (size_t)key0 * 8);
      g1.v = *(const bf16x8*)(gq + (size_t)key1 * 8);
      float bi0 = bb, bi1 = bb;
#pragma unroll
      for (int d = 0; d < 8; d++) {
        bi0 = fmaf(b2f(g0.u[d]), wcol[d], bi0);
        bi1 = fmaf(b2f(g1.u[d]), wcol[d], bi1);
      }
      sv0[r] = (k0c < SEQ) ? (s0[r] * 0.125f + bi0) : -1e30f;
      sv1[r] = (k1c < SEQ) ? (s1[r] * 0.125f + bi1) : -1e30f;
    }
    float tm[4];
#pragma unroll
    for (int r = 0; r < 4; r++) tm[r] = fmaxf(sv0[r], sv1[r]);
#pragma unroll
    for (int m = 1; m <= 8; m <<= 1)
#pragma unroll
      for (int r = 0; r < 4; r++) tm[r] = fmaxf(tm[r], __shfl_xor(tm[r], m));
    float alpha[4];
#pragma unroll
    for (int r = 0; r < 4; r++) {
      float mnew = fmaxf(mrun[r], tm[r]);
      alpha[r] = __expf(mrun[r] - mnew);
      mrun[r] = mnew;
    }
    float p0[4], p1[4], rsum[4];
#pragma unroll
    for (int r = 0; r < 4; r++) {
      p0[r] = __expf(sv0[r] - mrun[r]);
      p1[r] = __expf(sv1[r] - mrun[r]);
      rsum[r] = p0[r] + p1[r];
    }
#pragma unroll
    for (int m = 1; m <= 8; m <<= 1)
#pragma unroll
      for (int r = 0; r < 4; r++) rsum[r] += __shfl_xor(rsum[r], m);
#pragma unroll
    for (int r = 0; r < 4; r++) lrun[r] = lrun[r] * alpha[r] + rsum[r];
#pragma unroll
    for (int nt = 0; nt < 4; nt++)
#pragma unroll
      for (int r = 0; r < 4; r++) acc[nt][r] *= alpha[r];

    __syncthreads();  // previous iter's P/Vt reads complete
    u16* pw = &P[wave][0];
#pragma unroll
    for (int r = 0; r < 4; r++) {
      int prow = quad * 4 + r;
      pw[prow * 32 + lh]      = f2b(p0[r]);
      pw[prow * 32 + 16 + lh] = f2b(p1[r]);
    }
#pragma unroll
    for (int j = 0; j < 8; j++) Vt[(vd0 + j) * 40 + vkid] = vst.u[j];
    __syncthreads();  // P + Vt visible
    bf16x8 ap = *(const bf16x8*)&P[wave][lh * 32 + quad * 8];

#pragma unroll
    for (int nt = 0; nt < 4; nt++) {
      bf16x8 vb = *(const bf16x8*)&Vt[(nt * 16 + lh) * 40 + quad * 8];
      acc[nt] = __builtin_amdgcn_mfma_f32_16x16x32_bf16(ap, vb, acc[nt], 0, 0, 0);
    }
  }

#pragma unroll
  for (int nt = 0; nt < 4; nt++)
#pragma unroll
    for (int r = 0; r < 4; r++) {
      int qq = q0 + quad * 4 + r;
      if (qq < SEQ) {
        float o = acc[nt][r] / lrun[r];
        obf[((size_t)b * SEQ + qq) * HDIM + head * DHEAD + nt * 16 + lh] = f2b(o);
      }
    }
}

// ---------------- final LN + readout + log_softmax ----------------
__global__ __launch_bounds__(256) void k_readout(const float* __restrict__ h,
    const float* __restrict__ fg, const float* __restrict__ fb,
    const float* __restrict__ outW, const float* __restrict__ outb, float* __restrict__ out) {
  int b = blockIdx.x;
  const float* x = h + (size_t)b * SEQ * HDIM;  // node 0 row
  int t = threadIdx.x;
  float v0 = x[t], v1 = x[t + 256], v2 = x[t + 512];
  float s = v0 + v1 + v2, q = v0*v0 + v1*v1 + v2*v2;
#pragma unroll
  for (int m = 32; m >= 1; m >>= 1) { s += __shfl_xor(s, m); q += __shfl_xor(q, m); }
  __shared__ float ss[4], qq[4];
  int w = t >> 6, lane = t & 63;
  if (lane == 0) { ss[w] = s; qq[w] = q; }
  __syncthreads();
  s = ss[0] + ss[1] + ss[2] + ss[3];
  q = qq[0] + qq[1] + qq[2] + qq[3];
  float mean = s * (1.0f / HDIM);
  float var = q * (1.0f / HDIM) - mean * mean;
  float rs = rsqrtf(var + 1e-5f);
  __shared__ float yn[HDIM];
  yn[t]       = (v0 - mean) * rs * fg[t]       + fb[t];
  yn[t + 256] = (v1 - mean) * rs * fg[t + 256] + fb[t + 256];
  yn[t + 512] = (v2 - mean) * rs * fg[t + 512] + fb[t + 512];
  __syncthreads();
  __shared__ float lg[OUTC];
  for (int j = w; j < OUTC; j += 4) {
    float p = 0.f;
    for (int d = lane; d < HDIM; d += 64) p += yn[d] * outW[(size_t)d * OUTC + j];
#pragma unroll
    for (int m = 32; m >= 1; m >>= 1) p += __shfl_xor(p, m);
    if (lane == 0) lg[j] = p + outb[j];
  }
  __syncthreads();
  if (t == 0) {
    float mx = lg[0];
    for (int j = 1; j < OUTC; j++) mx = fmaxf(mx, lg[j]);
    float se = 0.f;
    for (int j = 0; j < OUTC; j++) se += expf(lg[j] - mx);
    float lse = mx + logf(se);
    for (int j = 0; j < OUTC; j++) out[b * OUTC + j] = lg[j] - lse;
  }
}

extern "C" void kernel_launch(void* const* d_in, const int* in_sizes, int n_in,
                              void* d_out, int out_size, void* d_ws, size_t ws_size,
                              hipStream_t stream) {
  const float* attn_bias = (const float*)d_in[0];
  const float* x      = (const float*)d_in[1];
  const float* enc_W  = (const float*)d_in[2];
  const float* enc_b  = (const float*)d_in[3];
  const float* gtok   = (const float*)d_in[4];
  const float* gvd    = (const float*)d_in[5];
  const float* ln1_g  = (const float*)d_in[6];
  const float* ln1_b  = (const float*)d_in[7];
  const float* Wq     = (const float*)d_in[8];
  const float* bq     = (const float*)d_in[9];
  const float* Wk     = (const float*)d_in[10];
  const float* bk     = (const float*)d_in[11];
  const float* Wv     = (const float*)d_in[12];
  const float* bv     = (const float*)d_in[13];
  const float* Wbias  = (const float*)d_in[14];
  const float* bbias  = (const float*)d_in[15];
  const float* Wo     = (const float*)d_in[16];
  const float* bo     = (const float*)d_in[17];
  const float* ln2_g  = (const float*)d_in[18];
  const float* ln2_b  = (const float*)d_in[19];
  const float* W1     = (const float*)d_in[20];
  const float* b1     = (const float*)d_in[21];
  const float* W2     = (const float*)d_in[22];
  const float* b2     = (const float*)d_in[23];
  const float* fln_g  = (const float*)d_in[24];
  const float* fln_b  = (const float*)d_in[25];
  const float* out_W  = (const float*)d_in[26];
  const float* out_b  = (const float*)d_in[27];
  float* out = (float*)d_out;
  (void)in_sizes; (void)n_in; (void)out_size; (void)ws_size;

  char* ws = (char*)d_ws;
  size_t off = 0;
  auto alloc = [&](size_t bytes) -> char* {
    char* p = ws + off; off += (bytes + 255) & ~(size_t)255; return p;
  };
  u16* wqkvt = (u16*)alloc((size_t)LAYERS * QKVW * HDIM * 2);
  u16* wot   = (u16*)alloc((size_t)LAYERS * HDIM * HDIM * 2);
  u16* w1t   = (u16*)alloc((size_t)LAYERS * FFDIM * HDIM * 2);
  u16* w2t   = (u16*)alloc((size_t)LAYERS * HDIM * FFDIM * 2);
  u16* encwt = (u16*)alloc((size_t)HDIM * INDIM * 2);
  u16* xb    = (u16*)alloc((size_t)MROWS0 * INDIM * 2);
  float* hb  = (float*)alloc((size_t)MROWS * HDIM * 4);
  u16* yb    = (u16*)alloc((size_t)MROWS * HDIM * 2);
  u16* qkvb  = (u16*)alloc((size_t)MROWS * QKVW * 2);
  u16* ob    = (u16*)alloc((size_t)MROWS * HDIM * 2);
  u16* gb8   = (u16*)alloc((size_t)BB * SEQ * SEQ * 8 * 2);
  // ffn buffer exactly aliases [qkvb|ob] (7184*2304 + 7184*768 == 7184*3072 bf16),
  // lifetime-disjoint: ffn1 writes after attention/Wo consumed qkv & o.
  u16* ffnb  = qkvb;

  // weights -> bf16 transposed (N,K)
  k_transpose_qkv<<<dim3(24, 24, 18), 256, 0, stream>>>(Wq, Wk, Wv, wqkvt);
  k_transpose_b<<<dim3(24, 24, 6), 256, 0, stream>>>(Wo, wot, HDIM, HDIM);
  k_transpose_b<<<dim3(96, 24, 6), 256, 0, stream>>>(W1, w1t, HDIM, FFDIM);
  k_transpose_b<<<dim3(24, 96, 6), 256, 0, stream>>>(W2, w2t, FFDIM, HDIM);
  k_transpose_b<<<dim3(24, 4, 1), 256, 0, stream>>>(enc_W, encwt, INDIM, HDIM);
  k_cvt<<<dim3((MROWS0 * INDIM) / 256), 256, 0, stream>>>(x, xb, MROWS0 * INDIM);
  k_gb<<<dim3(BB * SEQ), 256, 0, stream>>>(attn_bias, gvd, gb8);

  // grid size helper: NBMp (m-tiles padded to 8) x nbn, 1D
  auto ggrid = [](int M, int nbn) { int nbm = (M + 127) / 128; int nbmp = (nbm + 7) & ~7;
                                    return nbmp * nbn; };

  // node encode + graph token
  k_gemm<<<dim3(ggrid(MROWS0, 6)), 256, 0, stream>>>(xb, encwt, MROWS0, INDIM, 6, 0,
      enc_b, nullptr, nullptr, hb, nullptr);
  k_token<<<dim3(BB), 256, 0, stream>>>(gtok, hb);

  for (int l = 0; l < LAYERS; l++) {
    k_ln<<<dim3(MROWS), 256, 0, stream>>>(hb, ln1_g + l * HDIM, ln1_b + l * HDIM, yb);
    k_gemm<<<dim3(ggrid(MROWS, 18)), 256, 0, stream>>>(yb, wqkvt + (size_t)l * QKVW * HDIM,
        MROWS, HDIM, 18, 1, bq + l * HDIM, bk + l * HDIM, bv + l * HDIM, nullptr, qkvb);
    k_attn<<<dim3(96, BB), 256, 0, stream>>>(qkvb, gb8,
        Wbias + l * BDIM * NHEADS, bbias + l * NHEADS, ob);
    k_gemm<<<dim3(ggrid(MROWS, 6)), 256, 0, stream>>>(ob, wot + (size_t)l * HDIM * HDIM,
        MROWS, HDIM, 6, 2, bo + l * HDIM, nullptr, nullptr, hb, nullptr);
    k_ln<<<dim3(MROWS), 256, 0, stream>>>(hb, ln2_g + l * HDIM, ln2_b + l * HDIM, yb);
    k_gemm<<<dim3(ggrid(MROWS, 24)), 256, 0, stream>>>(yb, w1t + (size_t)l * FFDIM * HDIM,
        MROWS, HDIM, 24, 3, b1 + l * FFDIM, nullptr, nullptr, nullptr, ffnb);
    k_gemm<<<dim3(ggrid(MROWS, 6)), 256, 0, stream>>>(ffnb, w2t + (size_t)l * HDIM * FFDIM,
        MROWS, FFDIM, 6, 4, b2 + l * HDIM, nullptr, nullptr, hb, nullptr);
  }
  k_readout<<<dim3(BB), 256, 0, stream>>>(hb, fln_g, fln_b, out_W, out_b, out);
}

// Round 3
// 2940.007 us; speedup vs baseline: 1.0737x; 1.0737x over previous
//
#include <hip/hip_runtime.h>
#include <math.h>

typedef unsigned short u16;
typedef unsigned int u32;
typedef float f32x4 __attribute__((ext_vector_type(4)));
typedef __bf16 bf16x8 __attribute__((ext_vector_type(8)));

#define LAYERS 6
#define NHEADS 12
#define INDIM 128
#define HDIM 768
#define OUTC 10
#define BDIM 8
#define FFDIM 3072
#define BB 16
#define NNODE 448
#define SEQ 449
#define DHEAD 64
#define MROWS (BB*SEQ)      // 7184
#define MROWS0 (BB*NNODE)   // 7168
#define QKVW 2304

__device__ __forceinline__ u16 f2b(float f) {
  u32 u = __float_as_uint(f);
  u32 r = (u + 0x7fffu + ((u >> 16) & 1u)) >> 16;
  return (u16)r;
}
__device__ __forceinline__ float b2f(u16 h) {
  return __uint_as_float(((u32)h) << 16);
}

// fast exact-enough erf (A&S 7.1.26, |abs err| < 1.5e-7 — far below bf16 quantum)
__device__ __forceinline__ float fast_erf(float x) {
  float ax = fabsf(x);
  float t = __builtin_amdgcn_rcpf(1.0f + 0.3275911f * ax);
  float poly = t * (0.254829592f + t * (-0.284496736f + t * (1.421413741f +
               t * (-1.453152027f + t * 1.061405429f))));
  float er = 1.0f - poly * __expf(-ax * ax);
  return copysignf(er, x);
}

// direct global->LDS DMA, 16B per lane. LDS dest = wave-uniform base + lane*16.
__device__ __forceinline__ void gload16(const u16* g, u16* l) {
  __builtin_amdgcn_global_load_lds((const __attribute__((address_space(1))) void*)g,
                                   (__attribute__((address_space(3))) void*)l,
                                   16, 0, 0);
}

// ---------------- transpose + fp32->bf16 convert: in (K,N) -> out (N,K) ----------------
__device__ __forceinline__ void tile_transpose(const float* in, u16* out, int K, int N,
                                               float (*sm)[33]) {
  int n0 = blockIdx.x * 32, k0 = blockIdx.y * 32;
  int tx = threadIdx.x & 31, ty = threadIdx.x >> 5;
#pragma unroll
  for (int r = 0; r < 4; r++)
    sm[ty + 8*r][tx] = in[(size_t)(k0 + ty + 8*r) * N + n0 + tx];
  __syncthreads();
#pragma unroll
  for (int r = 0; r < 4; r++)
    out[(size_t)(n0 + ty + 8*r) * K + k0 + tx] = f2b(sm[tx][ty + 8*r]);
}

__global__ __launch_bounds__(256) void k_transpose_b(const float* __restrict__ in,
                                                     u16* __restrict__ out, int K, int N) {
  __shared__ float sm[32][33];
  in  += (size_t)blockIdx.z * K * N;
  out += (size_t)blockIdx.z * K * N;
  tile_transpose(in, out, K, N, sm);
}

__global__ __launch_bounds__(256) void k_transpose_qkv(const float* __restrict__ Wq,
    const float* __restrict__ Wk, const float* __restrict__ Wv, u16* __restrict__ out) {
  __shared__ float sm[32][33];
  int z = blockIdx.z; int l = z / 3, m = z - 3 * l;
  const float* in = (m == 0 ? Wq : (m == 1 ? Wk : Wv)) + (size_t)l * HDIM * HDIM;
  u16* o = out + (size_t)l * QKVW * HDIM + (size_t)m * HDIM * HDIM;
  tile_transpose(in, o, HDIM, HDIM, sm);
}

__global__ __launch_bounds__(256) void k_cvt(const float* __restrict__ in,
                                             u16* __restrict__ out, int n) {
  int i = blockIdx.x * 256 + threadIdx.x;
  if (i < n) out[i] = f2b(in[i]);
}

__global__ __launch_bounds__(256) void k_token(const float* __restrict__ gt, float* __restrict__ h) {
  int b = blockIdx.x;
  for (int d = threadIdx.x; d < HDIM; d += 256)
    h[((size_t)b * SEQ + NNODE) * HDIM + d] = gt[d];
}

// ---------------- LayerNorm: h fp32 row -> y bf16 row ----------------
__global__ __launch_bounds__(256) void k_ln(const float* __restrict__ h, const float* __restrict__ g,
                                            const float* __restrict__ bta, u16* __restrict__ y) {
  int row = blockIdx.x;
  const float* x = h + (size_t)row * HDIM;
  int t = threadIdx.x;
  float v0 = x[t], v1 = x[t + 256], v2 = x[t + 512];
  float s = v0 + v1 + v2;
  float q = v0*v0 + v1*v1 + v2*v2;
#pragma unroll
  for (int m = 32; m >= 1; m >>= 1) { s += __shfl_xor(s, m); q += __shfl_xor(q, m); }
  __shared__ float ss[4], qq[4];
  int w = t >> 6;
  if ((t & 63) == 0) { ss[w] = s; qq[w] = q; }
  __syncthreads();
  s = ss[0] + ss[1] + ss[2] + ss[3];
  q = qq[0] + qq[1] + qq[2] + qq[3];
  float mean = s * (1.0f / HDIM);
  float var = q * (1.0f / HDIM) - mean * mean;
  float rs = rsqrtf(var + 1e-5f);
  u16* yr = y + (size_t)row * HDIM;
  yr[t]       = f2b((v0 - mean) * rs * g[t]       + bta[t]);
  yr[t + 256] = f2b((v1 - mean) * rs * g[t + 256] + bta[t + 256]);
  yr[t + 512] = f2b((v2 - mean) * rs * g[t + 512] + bta[t + 512]);
}

// ---------------- bf16 MFMA GEMM: C(M,N) = A(M,K) * Bt(N,K)^T ----------------
// 2-phase double-buffered K-loop: issue next tile's global_load_lds right
// AFTER the barrier, then compute the current tile — the barrier's vmcnt(0)
// drain lands after a full compute phase has hidden the load latency.
// T2 both-sides chunk swizzle (chunk ^= row&7) on the GLOBAL source during
// staging and on the ds_read_b128 address -> conflict-free with linear LDS.
// mode 0: enc  -> hbuf fp32 with (b,448-node)->(b,449-row) remap, +bias0
// mode 1: qkv  -> obf bf16 stride 2304, bias = concat(bq,bk,bv)
// mode 2: Wo   -> hbuf += acc + bias0
// mode 3: ffn1 -> obf bf16 stride 3072, fast-exact GELU(acc+bias0)
// mode 4: ffn2 -> hbuf += acc + bias0
__global__ __launch_bounds__(256) void k_gemm(const u16* __restrict__ A, const u16* __restrict__ Bt,
    int M, int Kd, int nbn, int mode,
    const float* __restrict__ bias0, const float* __restrict__ bias1, const float* __restrict__ bias2,
    float* __restrict__ hbuf, u16* __restrict__ obf) {
  int lin = blockIdx.x;
  int grpsz = nbn * 8;
  int grp = lin / grpsz;
  int rem = lin - grp * grpsz;
  int bn = rem >> 3;
  int bm = grp * 8 + (rem & 7);
  if (bm * 128 >= M) return;

  __shared__ __align__(16) u16 As[2][128 * 64];
  __shared__ __align__(16) u16 Bs[2][128 * 64];
  int tid = threadIdx.x;
  int lane = tid & 63, wave = tid >> 6;
  int wm = wave >> 1, wn = wave & 1;
  int lh = lane & 15, quad = lane >> 4;

  f32x4 zero4 = {0.f, 0.f, 0.f, 0.f};
  f32x4 acc[4][4];
#pragma unroll
  for (int i = 0; i < 4; i++)
#pragma unroll
    for (int j = 0; j < 4; j++) acc[i][j] = zero4;

  // staging map: wave w, round r covers LDS rows [w*32+r*8, +8); lane l ->
  // row w*32+r*8+(l>>3), LDS chunk l&7, GLOBAL chunk (l&7)^(l>>3)  (row&7 == l>>3)
  int schunk = ((lane & 7) ^ (lane >> 3)) * 8;  // u16 units, 16B chunks
  const u16* pa[4];
  const u16* pb[4];
#pragma unroll
  for (int r = 0; r < 4; r++) {
    int ar = bm * 128 + wave * 32 + r * 8 + (lane >> 3);
    if (ar > M - 1) ar = M - 1;  // duplicate row; outputs masked at epilogue
    pa[r] = A + (size_t)ar * Kd + schunk;
    int br = bn * 128 + wave * 32 + r * 8 + (lane >> 3);  // N always multiple of 128
    pb[r] = Bt + (size_t)br * Kd + schunk;
  }
  int ldsb = wave * 2048;  // u16 idx: wave*4096 bytes

  auto stage = [&](int bufi) {
#pragma unroll
    for (int r = 0; r < 4; r++) {
      gload16(pa[r], &As[bufi][ldsb + r * 512]);
      gload16(pb[r], &Bs[bufi][ldsb + r * 512]);
      pa[r] += 64; pb[r] += 64;
    }
  };
  auto compute = [&](int bufi) {
#pragma unroll
    for (int ks = 0; ks < 2; ks++) {
      int cs = (((ks * 4 + quad) ^ (lh & 7)) * 8);  // read-side swizzle (row&7 == lh&7)
      bf16x8 af[4], bfr[4];
#pragma unroll
      for (int mt = 0; mt < 4; mt++)
        af[mt] = *(const bf16x8*)&As[bufi][(wm * 64 + mt * 16 + lh) * 64 + cs];
#pragma unroll
      for (int nt = 0; nt < 4; nt++)
        bfr[nt] = *(const bf16x8*)&Bs[bufi][(wn * 64 + nt * 16 + lh) * 64 + cs];
#pragma unroll
      for (int mt = 0; mt < 4; mt++)
#pragma unroll
        for (int nt = 0; nt < 4; nt++)
          acc[mt][nt] = __builtin_amdgcn_mfma_f32_16x16x32_bf16(af[mt], bfr[nt], acc[mt][nt], 0, 0, 0);
    }
  };

  int kiters = Kd >> 6;  // always even (2 / 12 / 48)
  stage(0);              // prologue: tile 0
  for (int kt = 0; kt < kiters; kt += 2) {
    __syncthreads();     // vmcnt(0) drain -> buf0 staged; prior reads of buf1 done
    stage(1);            // tile kt+1 (exists: kiters even)
    compute(0);          // hides tile kt+1's load latency
    __syncthreads();     // buf1 ready; prior reads of buf0 done
    if (kt + 2 < kiters) stage(0);  // tile kt+2
    compute(1);
  }

#pragma unroll
  for (int mt = 0; mt < 4; mt++) {
#pragma unroll
    for (int nt = 0; nt < 4; nt++) {
      f32x4 v = acc[mt][nt];
      int gc = bn * 128 + wn * 64 + nt * 16 + lh;
#pragma unroll
      for (int r = 0; r < 4; r++) {
        int gr = bm * 128 + wm * 64 + mt * 16 + quad * 4 + r;
        if (gr >= M) continue;
        float val = v[r];
        if (mode == 0) {
          int b = gr / NNODE, sNode = gr - b * NNODE;
          hbuf[((size_t)(b * SEQ + sNode)) * HDIM + gc] = val + bias0[gc];
        } else if (mode == 1) {
          float bias = (gc < 768) ? bias0[gc] : ((gc < 1536) ? bias1[gc - 768] : bias2[gc - 1536]);
          obf[(size_t)gr * QKVW + gc] = f2b(val + bias);
        } else if (mode == 3) {
          float tt = val + bias0[gc];
          float gg = 0.5f * tt * (1.0f + fast_erf(tt * 0.70710678f));
          obf[(size_t)gr * FFDIM + gc] = f2b(gg);
        } else {  // mode 2 / 4: residual accumulate
          size_t p = (size_t)gr * HDIM + gc;
          hbuf[p] += val + bias0[gc];
        }
      }
    }
  }
}

// ---------------- one-time compact pair bias: gb8 (B,S,S,8) bf16 ----------------
__global__ __launch_bounds__(256) void k_gb(const float* __restrict__ ab,
    const float* __restrict__ gvd, u16* __restrict__ gb8) {
  int blk = blockIdx.x;               // b*SEQ + q
  int b = blk / SEQ, q = blk - b * SEQ;
  float4 gv0 = *(const float4*)gvd;
  float4 gv1 = *(const float4*)(gvd + 4);
  for (int k = threadIdx.x; k < SEQ; k += 256) {
    float4 d0, d1;
    if (q < NNODE && k < NNODE) {
      const float* src = ab + (((size_t)b * NNODE + q) * NNODE + k) * BDIM;
      d0 = *(const float4*)src; d1 = *(const float4*)(src + 4);
    } else { d0 = gv0; d1 = gv1; }
    u16 o[8] = {f2b(d0.x), f2b(d0.y), f2b(d0.z), f2b(d0.w),
                f2b(d1.x), f2b(d1.y), f2b(d1.z), f2b(d1.w)};
    *(uint4*)&gb8[((size_t)blk * SEQ + k) * 8] = *(uint4*)o;
  }
}

// ---------------- per-layer bias table: bias[b,h,q,k] = gb8[b,q,k,:].Wbias[:,h] + bbias[h] ----
// Streaming BW kernel (~129 MB/layer). Removes the 12x-redundant gb8 refetch
// and ~128 VALU ops per k-chunk per lane from the attention inner loop.
__global__ __launch_bounds__(256) void k_bias(const u16* __restrict__ gb8,
    const float* __restrict__ wbias, const float* __restrict__ bbv,
    u16* __restrict__ bias) {
  int b = blockIdx.y;
  int p = blockIdx.x * 256 + threadIdx.x;   // q*SEQ + k
  if (p >= SEQ * SEQ) return;
  union { bf16x8 v; u16 u[8]; } g;
  g.v = *(const bf16x8*)(gb8 + ((size_t)b * SEQ * SEQ + p) * 8);
  float gv[8];
#pragma unroll
  for (int d = 0; d < 8; d++) gv[d] = b2f(g.u[d]);
#pragma unroll
  for (int h = 0; h < NHEADS; h++) {
    float s = bbv[h];
#pragma unroll
    for (int d = 0; d < 8; d++) s = fmaf(gv[d], wbias[d * NHEADS + h], s);
    bias[(size_t)(b * NHEADS + h) * SEQ * SEQ + p] = f2b(s);
  }
}

// ---------------- flash attention, bias from precomputed table ----------------
// grid.x = qtile*12 + head. V tile (32 keys x 64 d) staged per k-chunk into
// LDS transposed (Vt[d][key-chunk-swizzled], stride 40). Key-chunk XOR
// swizzle c' = (v>>3) ^ ((d>>3)&3) on BOTH write and read sides cuts the
// staging-write bank conflict from 16-way to 4-way while keeping the b128
// read 16B-aligned. V global load issued early (T14) so latency hides under
// QK^T + softmax.
__global__ __launch_bounds__(256) void k_attn(const u16* __restrict__ qkv,
    const u16* __restrict__ bias, u16* __restrict__ obf) {
  int head = blockIdx.x % 12, qt = blockIdx.x / 12;
  int b = blockIdx.y;
  int wave = threadIdx.x >> 6, lane = threadIdx.x & 63;
  int tid = threadIdx.x;
  int lh = lane & 15, quad = lane >> 4;
  int q0 = qt * 64 + wave * 16;

  __shared__ __align__(16) u16 P[4][16 * 32];
  __shared__ __align__(16) u16 Vt[64 * 40];  // [d][swizzled key] stride 40

  const u16* Qb = qkv + head * DHEAD;
  const u16* Kb = qkv + 768 + head * DHEAD;
  const u16* Vb = qkv + 1536 + head * DHEAD;
  const u16* bias_b = bias + (size_t)(b * NHEADS + head) * SEQ * SEQ;

  int qr = q0 + lh; if (qr > NNODE) qr = NNODE;
  size_t qrow = ((size_t)b * SEQ + qr) * QKVW;
  bf16x8 aq0 = *(const bf16x8*)(Qb + qrow + quad * 8);
  bf16x8 aq1 = *(const bf16x8*)(Qb + qrow + 32 + quad * 8);

  // V staging map: thread t -> key kbase+(t>>3), dims (t&7)*8 .. +8
  int vkid = tid >> 3;          // key within chunk tile (0..31)
  int vd0 = (tid & 7) * 8;      // d base (0..56)
  // swizzled LDS column for this thread's 8 writes (d>>3 const: = vd0>>3)
  int vcc = (((vkid >> 3) ^ ((vd0 >> 3) & 3)) << 3) | (vkid & 7);

  f32x4 zero4 = {0.f, 0.f, 0.f, 0.f};
  float mrun[4], lrun[4];
  f32x4 acc[4];
#pragma unroll
  for (int r = 0; r < 4; r++) { mrun[r] = -3.0e38f; lrun[r] = 0.f; }
#pragma unroll
  for (int nt = 0; nt < 4; nt++) acc[nt] = zero4;

  int qrow_r[4];
#pragma unroll
  for (int r = 0; r < 4; r++) {
    int qq = q0 + quad * 4 + r; if (qq > NNODE) qq = NNODE;
    qrow_r[r] = qq;
  }

  for (int kc = 0; kc < 15; kc++) {
    int kbase = kc * 32;
    int key0 = kbase + lh;      if (key0 > NNODE) key0 = NNODE;
    int key1 = kbase + 16 + lh; if (key1 > NNODE) key1 = NNODE;
    size_t kr0 = ((size_t)b * SEQ + key0) * QKVW;
    size_t kr1 = ((size_t)b * SEQ + key1) * QKVW;
    bf16x8 bk00 = *(const bf16x8*)(Kb + kr0 + quad * 8);
    bf16x8 bk01 = *(const bf16x8*)(Kb + kr0 + 32 + quad * 8);
    bf16x8 bk10 = *(const bf16x8*)(Kb + kr1 + quad * 8);
    bf16x8 bk11 = *(const bf16x8*)(Kb + kr1 + 32 + quad * 8);

    // issue V tile load early; consumed at the LDS write after the barrier
    int vkey = kbase + vkid; if (vkey > NNODE) vkey = NNODE;
    union { bf16x8 v; u16 u[8]; } vst;
    vst.v = *(const bf16x8*)(Vb + ((size_t)b * SEQ + vkey) * QKVW + vd0);

    // bias reads (2B each, coalesced within 16-lane groups)
    float bi0[4], bi1[4];
#pragma unroll
    for (int r = 0; r < 4; r++) {
      const u16* br_ = bias_b + (size_t)qrow_r[r] * SEQ;
      bi0[r] = b2f(br_[key0]);
      bi1[r] = b2f(br_[key1]);
    }

    f32x4 s0 = __builtin_amdgcn_mfma_f32_16x16x32_bf16(aq0, bk00, zero4, 0, 0, 0);
    s0 = __builtin_amdgcn_mfma_f32_16x16x32_bf16(aq1, bk01, s0, 0, 0, 0);
    f32x4 s1 = __builtin_amdgcn_mfma_f32_16x16x32_bf16(aq0, bk10, zero4, 0, 0, 0);
    s1 = __builtin_amdgcn_mfma_f32_16x16x32_bf16(aq1, bk11, s1, 0, 0, 0);

    int k0c = kbase + lh, k1c = kbase + 16 + lh;
    float sv0[4], sv1[4];
#pragma unroll
    for (int r = 0; r < 4; r++) {
      sv0[r] = (k0c < SEQ) ? fmaf(s0[r], 0.125f, bi0[r]) : -1e30f;
      sv1[r] = (k1c < SEQ) ? fmaf(s1[r], 0.125f, bi1[r]) : -1e30f;
    }
    float tm[4];
#pragma unroll
    for (int r = 0; r < 4; r++) tm[r] = fmaxf(sv0[r], sv1[r]);
#pragma unroll
    for (int m = 1; m <= 8; m <<= 1)
#pragma unroll
      for (int r = 0; r < 4; r++) tm[r] = fmaxf(tm[r], __shfl_xor(tm[r], m));
    float alpha[4];
#pragma unroll
    for (int r = 0; r < 4; r++) {
      float mnew = fmaxf(mrun[r], tm[r]);
      alpha[r] = __expf(mrun[r] - mnew);
      mrun[r] = mnew;
    }
    float p0[4], p1[4], rsum[4];
#pragma unroll
    for (int r = 0; r < 4; r++) {
      p0[r] = __expf(sv0[r] - mrun[r]);
      p1[r] = __expf(sv1[r] - mrun[r]);
      rsum[r] = p0[r] + p1[r];
    }
#pragma unroll
    for (int m = 1; m <= 8; m <<= 1)
#pragma unroll
      for (int r = 0; r < 4; r++) rsum[r] += __shfl_xor(rsum[r], m);
#pragma unroll
    for (int r = 0; r < 4; r++) lrun[r] = lrun[r] * alpha[r] + rsum[r];
#pragma unroll
    for (int nt = 0; nt < 4; nt++)
#pragma unroll
      for (int r = 0; r < 4; r++) acc[nt][r] *= alpha[r];

    __syncthreads();  // previous iter's P/Vt reads complete
    u16* pw = &P[wave][0];
#pragma unroll
    for (int r = 0; r < 4; r++) {
      int prow = quad * 4 + r;
      pw[prow * 32 + lh]      = f2b(p0[r]);
      pw[prow * 32 + 16 + lh] = f2b(p1[r]);
    }
#pragma unroll
    for (int j = 0; j < 8; j++) Vt[(vd0 + j) * 40 + vcc] = vst.u[j];
    __syncthreads();  // P + Vt visible
    bf16x8 ap = *(const bf16x8*)&P[wave][lh * 32 + quad * 8];

#pragma unroll
    for (int nt = 0; nt < 4; nt++) {
      int d = nt * 16 + lh;
      int rc = (quad ^ ((d >> 3) & 3)) << 3;   // read-side key-chunk swizzle
      bf16x8 vb = *(const bf16x8*)&Vt[d * 40 + rc];
      acc[nt] = __builtin_amdgcn_mfma_f32_16x16x32_bf16(ap, vb, acc[nt], 0, 0, 0);
    }
  }

#pragma unroll
  for (int nt = 0; nt < 4; nt++)
#pragma unroll
    for (int r = 0; r < 4; r++) {
      int qq = q0 + quad * 4 + r;
      if (qq < SEQ) {
        float o = acc[nt][r] / lrun[r];
        obf[((size_t)b * SEQ + qq) * HDIM + head * DHEAD + nt * 16 + lh] = f2b(o);
      }
    }
}

// ---------------- final LN + readout + log_softmax ----------------
__global__ __launch_bounds__(256) void k_readout(const float* __restrict__ h,
    const float* __restrict__ fg, const float* __restrict__ fb,
    const float* __restrict__ outW, const float* __restrict__ outb, float* __restrict__ out) {
  int b = blockIdx.x;
  const float* x = h + (size_t)b * SEQ * HDIM;  // node 0 row
  int t = threadIdx.x;
  float v0 = x[t], v1 = x[t + 256], v2 = x[t + 512];
  float s = v0 + v1 + v2, q = v0*v0 + v1*v1 + v2*v2;
#pragma unroll
  for (int m = 32; m >= 1; m >>= 1) { s += __shfl_xor(s, m); q += __shfl_xor(q, m); }
  __shared__ float ss[4], qq[4];
  int w = t >> 6, lane = t & 63;
  if (lane == 0) { ss[w] = s; qq[w] = q; }
  __syncthreads();
  s = ss[0] + ss[1] + ss[2] + ss[3];
  q = qq[0] + qq[1] + qq[2] + qq[3];
  float mean = s * (1.0f / HDIM);
  float var = q * (1.0f / HDIM) - mean * mean;
  float rs = rsqrtf(var + 1e-5f);
  __shared__ float yn[HDIM];
  yn[t]       = (v0 - mean) * rs * fg[t]       + fb[t];
  yn[t + 256] = (v1 - mean) * rs * fg[t + 256] + fb[t + 256];
  yn[t + 512] = (v2 - mean) * rs * fg[t + 512] + fb[t + 512];
  __syncthreads();
  __shared__ float lg[OUTC];
  for (int j = w; j < OUTC; j += 4) {
    float p = 0.f;
    for (int d = lane; d < HDIM; d += 64) p += yn[d] * outW[(size_t)d * OUTC + j];
#pragma unroll
    for (int m = 32; m >= 1; m >>= 1) p += __shfl_xor(p, m);
    if (lane == 0) lg[j] = p + outb[j];
  }
  __syncthreads();
  if (t == 0) {
    float mx = lg[0];
    for (int j = 1; j < OUTC; j++) mx = fmaxf(mx, lg[j]);
    float se = 0.f;
    for (int j = 0; j < OUTC; j++) se += expf(lg[j] - mx);
    float lse = mx + logf(se);
    for (int j = 0; j < OUTC; j++) out[b * OUTC + j] = lg[j] - lse;
  }
}

extern "C" void kernel_launch(void* const* d_in, const int* in_sizes, int n_in,
                              void* d_out, int out_size, void* d_ws, size_t ws_size,
                              hipStream_t stream) {
  const float* attn_bias = (const float*)d_in[0];
  const float* x      = (const float*)d_in[1];
  const float* enc_W  = (const float*)d_in[2];
  const float* enc_b  = (const float*)d_in[3];
  const float* gtok   = (const float*)d_in[4];
  const float* gvd    = (const float*)d_in[5];
  const float* ln1_g  = (const float*)d_in[6];
  const float* ln1_b  = (const float*)d_in[7];
  const float* Wq     = (const float*)d_in[8];
  const float* bq     = (const float*)d_in[9];
  const float* Wk     = (const float*)d_in[10];
  const float* bk     = (const float*)d_in[11];
  const float* Wv     = (const float*)d_in[12];
  const float* bv     = (const float*)d_in[13];
  const float* Wbias  = (const float*)d_in[14];
  const float* bbias  = (const float*)d_in[15];
  const float* Wo     = (const float*)d_in[16];
  const float* bo     = (const float*)d_in[17];
  const float* ln2_g  = (const float*)d_in[18];
  const float* ln2_b  = (const float*)d_in[19];
  const float* W1     = (const float*)d_in[20];
  const float* b1     = (const float*)d_in[21];
  const float* W2     = (const float*)d_in[22];
  const float* b2     = (const float*)d_in[23];
  const float* fln_g  = (const float*)d_in[24];
  const float* fln_b  = (const float*)d_in[25];
  const float* out_W  = (const float*)d_in[26];
  const float* out_b  = (const float*)d_in[27];
  float* out = (float*)d_out;
  (void)in_sizes; (void)n_in; (void)out_size; (void)ws_size;

  char* ws = (char*)d_ws;
  size_t off = 0;
  auto alloc = [&](size_t bytes) -> char* {
    char* p = ws + off; off += (bytes + 255) & ~(size_t)255; return p;
  };
  u16* wqkvt = (u16*)alloc((size_t)LAYERS * QKVW * HDIM * 2);
  u16* wot   = (u16*)alloc((size_t)LAYERS * HDIM * HDIM * 2);
  u16* w1t   = (u16*)alloc((size_t)LAYERS * FFDIM * HDIM * 2);
  u16* w2t   = (u16*)alloc((size_t)LAYERS * HDIM * FFDIM * 2);
  u16* encwt = (u16*)alloc((size_t)HDIM * INDIM * 2);
  u16* xb    = (u16*)alloc((size_t)MROWS0 * INDIM * 2);
  float* hb  = (float*)alloc((size_t)MROWS * HDIM * 4);
  u16* yb    = (u16*)alloc((size_t)MROWS * HDIM * 2);
  u16* qkvb  = (u16*)alloc((size_t)MROWS * QKVW * 2);
  u16* ob    = (u16*)alloc((size_t)MROWS * HDIM * 2);
  u16* gb8   = (u16*)alloc((size_t)BB * SEQ * SEQ * 8 * 2);
  u16* biasb = (u16*)alloc((size_t)BB * NHEADS * SEQ * SEQ * 2);  // 77 MB, per-layer reuse
  // ffn buffer exactly aliases [qkvb|ob] (7184*2304 + 7184*768 == 7184*3072 bf16),
  // lifetime-disjoint: ffn1 writes after attention/Wo consumed qkv & o.
  u16* ffnb  = qkvb;

  // weights -> bf16 transposed (N,K)
  k_transpose_qkv<<<dim3(24, 24, 18), 256, 0, stream>>>(Wq, Wk, Wv, wqkvt);
  k_transpose_b<<<dim3(24, 24, 6), 256, 0, stream>>>(Wo, wot, HDIM, HDIM);
  k_transpose_b<<<dim3(96, 24, 6), 256, 0, stream>>>(W1, w1t, HDIM, FFDIM);
  k_transpose_b<<<dim3(24, 96, 6), 256, 0, stream>>>(W2, w2t, FFDIM, HDIM);
  k_transpose_b<<<dim3(24, 4, 1), 256, 0, stream>>>(enc_W, encwt, INDIM, HDIM);
  k_cvt<<<dim3((MROWS0 * INDIM) / 256), 256, 0, stream>>>(x, xb, MROWS0 * INDIM);
  k_gb<<<dim3(BB * SEQ), 256, 0, stream>>>(attn_bias, gvd, gb8);

  // grid size helper: NBMp (m-tiles padded to 8) x nbn, 1D
  auto ggrid = [](int M, int nbn) { int nbm = (M + 127) / 128; int nbmp = (nbm + 7) & ~7;
                                    return nbmp * nbn; };

  // node encode + graph token
  k_gemm<<<dim3(ggrid(MROWS0, 6)), 256, 0, stream>>>(xb, encwt, MROWS0, INDIM, 6, 0,
      enc_b, nullptr, nullptr, hb, nullptr);
  k_token<<<dim3(BB), 256, 0, stream>>>(gtok, hb);

  int nbias = (SEQ * SEQ + 255) / 256;
  for (int l = 0; l < LAYERS; l++) {
    k_ln<<<dim3(MROWS), 256, 0, stream>>>(hb, ln1_g + l * HDIM, ln1_b + l * HDIM, yb);
    k_gemm<<<dim3(ggrid(MROWS, 18)), 256, 0, stream>>>(yb, wqkvt + (size_t)l * QKVW * HDIM,
        MROWS, HDIM, 18, 1, bq + l * HDIM, bk + l * HDIM, bv + l * HDIM, nullptr, qkvb);
    k_bias<<<dim3(nbias, BB), 256, 0, stream>>>(gb8, Wbias + l * BDIM * NHEADS,
        bbias + l * NHEADS, biasb);
    k_attn<<<dim3(96, BB), 256, 0, stream>>>(qkvb, biasb, ob);
    k_gemm<<<dim3(ggrid(MROWS, 6)), 256, 0, stream>>>(ob, wot + (size_t)l * HDIM * HDIM,
        MROWS, HDIM, 6, 2, bo + l * HDIM, nullptr, nullptr, hb, nullptr);
    k_ln<<<dim3(MROWS), 256, 0, stream>>>(hb, ln2_g + l * HDIM, ln2_b + l * HDIM, yb);
    k_gemm<<<dim3(ggrid(MROWS, 24)), 256, 0, stream>>>(yb, w1t + (size_t)l * FFDIM * HDIM,
        MROWS, HDIM, 24, 3, b1 + l * FFDIM, nullptr, nullptr, nullptr, ffnb);
    k_gemm<<<dim3(ggrid(MROWS, 6)), 256, 0, stream>>>(ffnb, w2t + (size_t)l * HDIM * FFDIM,
        MROWS, FFDIM, 6, 4, b2 + l * HDIM, nullptr, nullptr, hb, nullptr);
  }
  k_readout<<<dim3(BB), 256, 0, stream>>>(hb, fln_g, fln_b, out_W, out_b, out);
}

// Round 4
// 2733.478 us; speedup vs baseline: 1.1548x; 1.0756x over previous
//
#include <hip/hip_runtime.h>
#include <math.h>

typedef unsigned short u16;
typedef unsigned int u32;
typedef float f32x4 __attribute__((ext_vector_type(4)));
typedef __bf16 bf16x8 __attribute__((ext_vector_type(8)));

#define LAYERS 6
#define NHEADS 12
#define INDIM 128
#define HDIM 768
#define OUTC 10
#define BDIM 8
#define FFDIM 3072
#define BB 16
#define NNODE 448
#define SEQ 449
#define DHEAD 64
#define MROWS (BB*SEQ)      // 7184
#define MROWS0 (BB*NNODE)   // 7168
#define QKVW 2304

__device__ __forceinline__ u16 f2b(float f) {
  u32 u = __float_as_uint(f);
  u32 r = (u + 0x7fffu + ((u >> 16) & 1u)) >> 16;
  return (u16)r;
}
__device__ __forceinline__ float b2f(u16 h) {
  return __uint_as_float(((u32)h) << 16);
}

// fast exact-enough erf (A&S 7.1.26, |abs err| < 1.5e-7 — far below bf16 quantum)
__device__ __forceinline__ float fast_erf(float x) {
  float ax = fabsf(x);
  float t = __builtin_amdgcn_rcpf(1.0f + 0.3275911f * ax);
  float poly = t * (0.254829592f + t * (-0.284496736f + t * (1.421413741f +
               t * (-1.453152027f + t * 1.061405429f))));
  float er = 1.0f - poly * __expf(-ax * ax);
  return copysignf(er, x);
}

// direct global->LDS DMA, 16B per lane. LDS dest = wave-uniform base + lane*16.
__device__ __forceinline__ void gload16(const u16* g, u16* l) {
  __builtin_amdgcn_global_load_lds((const __attribute__((address_space(1))) void*)g,
                                   (__attribute__((address_space(3))) void*)l,
                                   16, 0, 0);
}

// ---------------- transpose + fp32->bf16 convert: in (K,N) -> out (N,K) ----------------
__device__ __forceinline__ void tile_transpose(const float* in, u16* out, int K, int N,
                                               float (*sm)[33]) {
  int n0 = blockIdx.x * 32, k0 = blockIdx.y * 32;
  int tx = threadIdx.x & 31, ty = threadIdx.x >> 5;
#pragma unroll
  for (int r = 0; r < 4; r++)
    sm[ty + 8*r][tx] = in[(size_t)(k0 + ty + 8*r) * N + n0 + tx];
  __syncthreads();
#pragma unroll
  for (int r = 0; r < 4; r++)
    out[(size_t)(n0 + ty + 8*r) * K + k0 + tx] = f2b(sm[tx][ty + 8*r]);
}

__global__ __launch_bounds__(256) void k_transpose_b(const float* __restrict__ in,
                                                     u16* __restrict__ out, int K, int N) {
  __shared__ float sm[32][33];
  in  += (size_t)blockIdx.z * K * N;
  out += (size_t)blockIdx.z * K * N;
  tile_transpose(in, out, K, N, sm);
}

__global__ __launch_bounds__(256) void k_transpose_qkv(const float* __restrict__ Wq,
    const float* __restrict__ Wk, const float* __restrict__ Wv, u16* __restrict__ out) {
  __shared__ float sm[32][33];
  int z = blockIdx.z; int l = z / 3, m = z - 3 * l;
  const float* in = (m == 0 ? Wq : (m == 1 ? Wk : Wv)) + (size_t)l * HDIM * HDIM;
  u16* o = out + (size_t)l * QKVW * HDIM + (size_t)m * HDIM * HDIM;
  tile_transpose(in, o, HDIM, HDIM, sm);
}

__global__ __launch_bounds__(256) void k_cvt(const float* __restrict__ in,
                                             u16* __restrict__ out, int n) {
  int i = blockIdx.x * 256 + threadIdx.x;
  if (i < n) out[i] = f2b(in[i]);
}

__global__ __launch_bounds__(256) void k_token(const float* __restrict__ gt, float* __restrict__ h) {
  int b = blockIdx.x;
  for (int d = threadIdx.x; d < HDIM; d += 256)
    h[((size_t)b * SEQ + NNODE) * HDIM + d] = gt[d];
}

// ---------------- LayerNorm: h fp32 row -> y bf16 row ----------------
__global__ __launch_bounds__(256) void k_ln(const float* __restrict__ h, const float* __restrict__ g,
                                            const float* __restrict__ bta, u16* __restrict__ y) {
  int row = blockIdx.x;
  const float* x = h + (size_t)row * HDIM;
  int t = threadIdx.x;
  float v0 = x[t], v1 = x[t + 256], v2 = x[t + 512];
  float s = v0 + v1 + v2;
  float q = v0*v0 + v1*v1 + v2*v2;
#pragma unroll
  for (int m = 32; m >= 1; m >>= 1) { s += __shfl_xor(s, m); q += __shfl_xor(q, m); }
  __shared__ float ss[4], qq[4];
  int w = t >> 6;
  if ((t & 63) == 0) { ss[w] = s; qq[w] = q; }
  __syncthreads();
  s = ss[0] + ss[1] + ss[2] + ss[3];
  q = qq[0] + qq[1] + qq[2] + qq[3];
  float mean = s * (1.0f / HDIM);
  float var = q * (1.0f / HDIM) - mean * mean;
  float rs = rsqrtf(var + 1e-5f);
  u16* yr = y + (size_t)row * HDIM;
  yr[t]       = f2b((v0 - mean) * rs * g[t]       + bta[t]);
  yr[t + 256] = f2b((v1 - mean) * rs * g[t + 256] + bta[t + 256]);
  yr[t + 512] = f2b((v2 - mean) * rs * g[t + 512] + bta[t + 512]);
}

// ---------------- bf16 MFMA GEMM: C(M,N) = A(M,K) * Bt(N,K)^T ----------------
// Counted-vmcnt double-buffered K-loop (T4): prologue stages tiles 0 and 1
// (16 loads in flight); loop top waits vmcnt(8) — only the OLDEST 8 loads
// (current tile) — so the next tile's loads stay in flight ACROSS the
// barrier. Tile kt+2 is staged after the read-release barrier, giving each
// tile a full iteration (compute + 2 barriers) of latency cover instead of
// one compute phase. Raw s_barrier + inline-asm waitcnt; sched_barrier(0)
// pins at phase boundaries only (rule #18).
// T2 both-sides chunk swizzle (chunk ^= row&7) on the GLOBAL source during
// staging and on the ds_read_b128 address -> conflict-free with linear LDS.
// mode 0: enc  -> hbuf fp32 with (b,448-node)->(b,449-row) remap, +bias0
// mode 1: qkv  -> obf bf16 stride 2304, bias = concat(bq,bk,bv)
// mode 2: Wo   -> hbuf += acc + bias0
// mode 3: ffn1 -> obf bf16 stride 3072, fast-exact GELU(acc+bias0)
// mode 4: ffn2 -> hbuf += acc + bias0
__global__ __launch_bounds__(256) void k_gemm(const u16* __restrict__ A, const u16* __restrict__ Bt,
    int M, int Kd, int nbn, int mode,
    const float* __restrict__ bias0, const float* __restrict__ bias1, const float* __restrict__ bias2,
    float* __restrict__ hbuf, u16* __restrict__ obf) {
  int lin = blockIdx.x;
  int grpsz = nbn * 8;
  int grp = lin / grpsz;
  int rem = lin - grp * grpsz;
  int bn = rem >> 3;
  int bm = grp * 8 + (rem & 7);
  if (bm * 128 >= M) return;

  __shared__ __align__(16) u16 As[2][128 * 64];
  __shared__ __align__(16) u16 Bs[2][128 * 64];
  int tid = threadIdx.x;
  int lane = tid & 63, wave = tid >> 6;
  int wm = wave >> 1, wn = wave & 1;
  int lh = lane & 15, quad = lane >> 4;

  f32x4 zero4 = {0.f, 0.f, 0.f, 0.f};
  f32x4 acc[4][4];
#pragma unroll
  for (int i = 0; i < 4; i++)
#pragma unroll
    for (int j = 0; j < 4; j++) acc[i][j] = zero4;

  // staging map: wave w, round r covers LDS rows [w*32+r*8, +8); lane l ->
  // row w*32+r*8+(l>>3), LDS chunk l&7, GLOBAL chunk (l&7)^(l>>3)  (row&7 == l>>3)
  int schunk = ((lane & 7) ^ (lane >> 3)) * 8;  // u16 units, 16B chunks
  const u16* pa[4];
  const u16* pb[4];
#pragma unroll
  for (int r = 0; r < 4; r++) {
    int ar = bm * 128 + wave * 32 + r * 8 + (lane >> 3);
    if (ar > M - 1) ar = M - 1;  // duplicate row; outputs masked at epilogue
    pa[r] = A + (size_t)ar * Kd + schunk;
    int br = bn * 128 + wave * 32 + r * 8 + (lane >> 3);  // N always multiple of 128
    pb[r] = Bt + (size_t)br * Kd + schunk;
  }
  int ldsb = wave * 2048;  // u16 idx: wave*4096 bytes

  auto stage = [&](int bufi) {
#pragma unroll
    for (int r = 0; r < 4; r++) {
      gload16(pa[r], &As[bufi][ldsb + r * 512]);
      gload16(pb[r], &Bs[bufi][ldsb + r * 512]);
      pa[r] += 64; pb[r] += 64;
    }
  };
  auto compute = [&](int bufi) {
#pragma unroll
    for (int ks = 0; ks < 2; ks++) {
      int cs = (((ks * 4 + quad) ^ (lh & 7)) * 8);  // read-side swizzle (row&7 == lh&7)
      bf16x8 af[4], bfr[4];
#pragma unroll
      for (int mt = 0; mt < 4; mt++)
        af[mt] = *(const bf16x8*)&As[bufi][(wm * 64 + mt * 16 + lh) * 64 + cs];
#pragma unroll
      for (int nt = 0; nt < 4; nt++)
        bfr[nt] = *(const bf16x8*)&Bs[bufi][(wn * 64 + nt * 16 + lh) * 64 + cs];
#pragma unroll
      for (int mt = 0; mt < 4; mt++)
#pragma unroll
        for (int nt = 0; nt < 4; nt++)
          acc[mt][nt] = __builtin_amdgcn_mfma_f32_16x16x32_bf16(af[mt], bfr[nt], acc[mt][nt], 0, 0, 0);
    }
  };

  int kiters = Kd >> 6;  // >= 2 always (Kd: 128 / 768 / 3072)
  stage(0);              // tile 0 -> buf0 (8 loads)
  stage(1);              // tile 1 -> buf1 (8 more; 16 in flight)
  for (int kt = 0; kt < kiters; kt++) {
    int cur = kt & 1;
    if (kt < kiters - 1) {
      // wait only the oldest 8 loads (tile kt); tile kt+1's stay in flight
      asm volatile("s_waitcnt vmcnt(8)" ::: "memory");
    } else {
      asm volatile("s_waitcnt vmcnt(0)" ::: "memory");
    }
    __builtin_amdgcn_sched_barrier(0);
    __builtin_amdgcn_s_barrier();          // tile kt visible to all waves
    __builtin_amdgcn_sched_barrier(0);
    compute(cur);
    __builtin_amdgcn_sched_barrier(0);
    __builtin_amdgcn_s_barrier();          // all waves done reading buf[cur]
    __builtin_amdgcn_sched_barrier(0);
    if (kt + 2 < kiters) stage(cur);       // tile kt+2 -> buf[cur]
  }

#pragma unroll
  for (int mt = 0; mt < 4; mt++) {
#pragma unroll
    for (int nt = 0; nt < 4; nt++) {
      f32x4 v = acc[mt][nt];
      int gc = bn * 128 + wn * 64 + nt * 16 + lh;
#pragma unroll
      for (int r = 0; r < 4; r++) {
        int gr = bm * 128 + wm * 64 + mt * 16 + quad * 4 + r;
        if (gr >= M) continue;
        float val = v[r];
        if (mode == 0) {
          int b = gr / NNODE, sNode = gr - b * NNODE;
          hbuf[((size_t)(b * SEQ + sNode)) * HDIM + gc] = val + bias0[gc];
        } else if (mode == 1) {
          float bias = (gc < 768) ? bias0[gc] : ((gc < 1536) ? bias1[gc - 768] : bias2[gc - 1536]);
          obf[(size_t)gr * QKVW + gc] = f2b(val + bias);
        } else if (mode == 3) {
          float tt = val + bias0[gc];
          float gg = 0.5f * tt * (1.0f + fast_erf(tt * 0.70710678f));
          obf[(size_t)gr * FFDIM + gc] = f2b(gg);
        } else {  // mode 2 / 4: residual accumulate
          size_t p = (size_t)gr * HDIM + gc;
          hbuf[p] += val + bias0[gc];
        }
      }
    }
  }
}

// ---------------- one-time compact pair bias: gb8 (B,S,S,8) bf16 ----------------
__global__ __launch_bounds__(256) void k_gb(const float* __restrict__ ab,
    const float* __restrict__ gvd, u16* __restrict__ gb8) {
  int blk = blockIdx.x;               // b*SEQ + q
  int b = blk / SEQ, q = blk - b * SEQ;
  float4 gv0 = *(const float4*)gvd;
  float4 gv1 = *(const float4*)(gvd + 4);
  for (int k = threadIdx.x; k < SEQ; k += 256) {
    float4 d0, d1;
    if (q < NNODE && k < NNODE) {
      const float* src = ab + (((size_t)b * NNODE + q) * NNODE + k) * BDIM;
      d0 = *(const float4*)src; d1 = *(const float4*)(src + 4);
    } else { d0 = gv0; d1 = gv1; }
    u16 o[8] = {f2b(d0.x), f2b(d0.y), f2b(d0.z), f2b(d0.w),
                f2b(d1.x), f2b(d1.y), f2b(d1.z), f2b(d1.w)};
    *(uint4*)&gb8[((size_t)blk * SEQ + k) * 8] = *(uint4*)o;
  }
}

// ---------------- per-layer bias table: bias[b,h,q,k] = gb8[b,q,k,:].Wbias[:,h] + bbias[h] ----
__global__ __launch_bounds__(256) void k_bias(const u16* __restrict__ gb8,
    const float* __restrict__ wbias, const float* __restrict__ bbv,
    u16* __restrict__ bias) {
  int b = blockIdx.y;
  int p = blockIdx.x * 256 + threadIdx.x;   // q*SEQ + k
  if (p >= SEQ * SEQ) return;
  union { bf16x8 v; u16 u[8]; } g;
  g.v = *(const bf16x8*)(gb8 + ((size_t)b * SEQ * SEQ + p) * 8);
  float gv[8];
#pragma unroll
  for (int d = 0; d < 8; d++) gv[d] = b2f(g.u[d]);
#pragma unroll
  for (int h = 0; h < NHEADS; h++) {
    float s = bbv[h];
#pragma unroll
    for (int d = 0; d < 8; d++) s = fmaf(gv[d], wbias[d * NHEADS + h], s);
    bias[(size_t)(b * NHEADS + h) * SEQ * SEQ + p] = f2b(s);
  }
}

// ---------------- flash attention, bias from precomputed table ----------------
__global__ __launch_bounds__(256) void k_attn(const u16* __restrict__ qkv,
    const u16* __restrict__ bias, u16* __restrict__ obf) {
  int head = blockIdx.x % 12, qt = blockIdx.x / 12;
  int b = blockIdx.y;
  int wave = threadIdx.x >> 6, lane = threadIdx.x & 63;
  int tid = threadIdx.x;
  int lh = lane & 15, quad = lane >> 4;
  int q0 = qt * 64 + wave * 16;

  __shared__ __align__(16) u16 P[4][16 * 32];
  __shared__ __align__(16) u16 Vt[64 * 40];  // [d][swizzled key] stride 40

  const u16* Qb = qkv + head * DHEAD;
  const u16* Kb = qkv + 768 + head * DHEAD;
  const u16* Vb = qkv + 1536 + head * DHEAD;
  const u16* bias_b = bias + (size_t)(b * NHEADS + head) * SEQ * SEQ;

  int qr = q0 + lh; if (qr > NNODE) qr = NNODE;
  size_t qrow = ((size_t)b * SEQ + qr) * QKVW;
  bf16x8 aq0 = *(const bf16x8*)(Qb + qrow + quad * 8);
  bf16x8 aq1 = *(const bf16x8*)(Qb + qrow + 32 + quad * 8);

  // V staging map: thread t -> key kbase+(t>>3), dims (t&7)*8 .. +8
  int vkid = tid >> 3;          // key within chunk tile (0..31)
  int vd0 = (tid & 7) * 8;      // d base (0..56)
  int vcc = (((vkid >> 3) ^ ((vd0 >> 3) & 3)) << 3) | (vkid & 7);

  f32x4 zero4 = {0.f, 0.f, 0.f, 0.f};
  float mrun[4], lrun[4];
  f32x4 acc[4];
#pragma unroll
  for (int r = 0; r < 4; r++) { mrun[r] = -3.0e38f; lrun[r] = 0.f; }
#pragma unroll
  for (int nt = 0; nt < 4; nt++) acc[nt] = zero4;

  int qrow_r[4];
#pragma unroll
  for (int r = 0; r < 4; r++) {
    int qq = q0 + quad * 4 + r; if (qq > NNODE) qq = NNODE;
    qrow_r[r] = qq;
  }

  for (int kc = 0; kc < 15; kc++) {
    int kbase = kc * 32;
    int key0 = kbase + lh;      if (key0 > NNODE) key0 = NNODE;
    int key1 = kbase + 16 + lh; if (key1 > NNODE) key1 = NNODE;
    size_t kr0 = ((size_t)b * SEQ + key0) * QKVW;
    size_t kr1 = ((size_t)b * SEQ + key1) * QKVW;
    bf16x8 bk00 = *(const bf16x8*)(Kb + kr0 + quad * 8);
    bf16x8 bk01 = *(const bf16x8*)(Kb + kr0 + 32 + quad * 8);
    bf16x8 bk10 = *(const bf16x8*)(Kb + kr1 + quad * 8);
    bf16x8 bk11 = *(const bf16x8*)(Kb + kr1 + 32 + quad * 8);

    // issue V tile load early; consumed at the LDS write after the barrier
    int vkey = kbase + vkid; if (vkey > NNODE) vkey = NNODE;
    union { bf16x8 v; u16 u[8]; } vst;
    vst.v = *(const bf16x8*)(Vb + ((size_t)b * SEQ + vkey) * QKVW + vd0);

    // bias reads (2B each, coalesced within 16-lane groups)
    float bi0[4], bi1[4];
#pragma unroll
    for (int r = 0; r < 4; r++) {
      const u16* br_ = bias_b + (size_t)qrow_r[r] * SEQ;
      bi0[r] = b2f(br_[key0]);
      bi1[r] = b2f(br_[key1]);
    }

    f32x4 s0 = __builtin_amdgcn_mfma_f32_16x16x32_bf16(aq0, bk00, zero4, 0, 0, 0);
    s0 = __builtin_amdgcn_mfma_f32_16x16x32_bf16(aq1, bk01, s0, 0, 0, 0);
    f32x4 s1 = __builtin_amdgcn_mfma_f32_16x16x32_bf16(aq0, bk10, zero4, 0, 0, 0);
    s1 = __builtin_amdgcn_mfma_f32_16x16x32_bf16(aq1, bk11, s1, 0, 0, 0);

    int k0c = kbase + lh, k1c = kbase + 16 + lh;
    float sv0[4], sv1[4];
#pragma unroll
    for (int r = 0; r < 4; r++) {
      sv0[r] = (k0c < SEQ) ? fmaf(s0[r], 0.125f, bi0[r]) : -1e30f;
      sv1[r] = (k1c < SEQ) ? fmaf(s1[r], 0.125f, bi1[r]) : -1e30f;
    }
    float tm[4];
#pragma unroll
    for (int r = 0; r < 4; r++) tm[r] = fmaxf(sv0[r], sv1[r]);
#pragma unroll
    for (int m = 1; m <= 8; m <<= 1)
#pragma unroll
      for (int r = 0; r < 4; r++) tm[r] = fmaxf(tm[r], __shfl_xor(tm[r], m));
    float alpha[4];
#pragma unroll
    for (int r = 0; r < 4; r++) {
      float mnew = fmaxf(mrun[r], tm[r]);
      alpha[r] = __expf(mrun[r] - mnew);
      mrun[r] = mnew;
    }
    float p0[4], p1[4], rsum[4];
#pragma unroll
    for (int r = 0; r < 4; r++) {
      p0[r] = __expf(sv0[r] - mrun[r]);
      p1[r] = __expf(sv1[r] - mrun[r]);
      rsum[r] = p0[r] + p1[r];
    }
#pragma unroll
    for (int m = 1; m <= 8; m <<= 1)
#pragma unroll
      for (int r = 0; r < 4; r++) rsum[r] += __shfl_xor(rsum[r], m);
#pragma unroll
    for (int r = 0; r < 4; r++) lrun[r] = lrun[r] * alpha[r] + rsum[r];
#pragma unroll
    for (int nt = 0; nt < 4; nt++)
#pragma unroll
      for (int r = 0; r < 4; r++) acc[nt][r] *= alpha[r];

    __syncthreads();  // previous iter's P/Vt reads complete
    u16* pw = &P[wave][0];
#pragma unroll
    for (int r = 0; r < 4; r++) {
      int prow = quad * 4 + r;
      pw[prow * 32 + lh]      = f2b(p0[r]);
      pw[prow * 32 + 16 + lh] = f2b(p1[r]);
    }
#pragma unroll
    for (int j = 0; j < 8; j++) Vt[(vd0 + j) * 40 + vcc] = vst.u[j];
    __syncthreads();  // P + Vt visible
    bf16x8 ap = *(const bf16x8*)&P[wave][lh * 32 + quad * 8];

#pragma unroll
    for (int nt = 0; nt < 4; nt++) {
      int d = nt * 16 + lh;
      int rc = (quad ^ ((d >> 3) & 3)) << 3;   // read-side key-chunk swizzle
      bf16x8 vb = *(const bf16x8*)&Vt[d * 40 + rc];
      acc[nt] = __builtin_amdgcn_mfma_f32_16x16x32_bf16(ap, vb, acc[nt], 0, 0, 0);
    }
  }

#pragma unroll
  for (int nt = 0; nt < 4; nt++)
#pragma unroll
    for (int r = 0; r < 4; r++) {
      int qq = q0 + quad * 4 + r;
      if (qq < SEQ) {
        float o = acc[nt][r] / lrun[r];
        obf[((size_t)b * SEQ + qq) * HDIM + head * DHEAD + nt * 16 + lh] = f2b(o);
      }
    }
}

// ---------------- final LN + readout + log_softmax ----------------
__global__ __launch_bounds__(256) void k_readout(const float* __restrict__ h,
    const float* __restrict__ fg, const float* __restrict__ fb,
    const float* __restrict__ outW, const float* __restrict__ outb, float* __restrict__ out) {
  int b = blockIdx.x;
  const float* x = h + (size_t)b * SEQ * HDIM;  // node 0 row
  int t = threadIdx.x;
  float v0 = x[t], v1 = x[t + 256], v2 = x[t + 512];
  float s = v0 + v1 + v2, q = v0*v0 + v1*v1 + v2*v2;
#pragma unroll
  for (int m = 32; m >= 1; m >>= 1) { s += __shfl_xor(s, m); q += __shfl_xor(q, m); }
  __shared__ float ss[4], qq[4];
  int w = t >> 6, lane = t & 63;
  if (lane == 0) { ss[w] = s; qq[w] = q; }
  __syncthreads();
  s = ss[0] + ss[1] + ss[2] + ss[3];
  q = qq[0] + qq[1] + qq[2] + qq[3];
  float mean = s * (1.0f / HDIM);
  float var = q * (1.0f / HDIM) - mean * mean;
  float rs = rsqrtf(var + 1e-5f);
  __shared__ float yn[HDIM];
  yn[t]       = (v0 - mean) * rs * fg[t]       + fb[t];
  yn[t + 256] = (v1 - mean) * rs * fg[t + 256] + fb[t + 256];
  yn[t + 512] = (v2 - mean) * rs * fg[t + 512] + fb[t + 512];
  __syncthreads();
  __shared__ float lg[OUTC];
  for (int j = w; j < OUTC; j += 4) {
    float p = 0.f;
    for (int d = lane; d < HDIM; d += 64) p += yn[d] * outW[(size_t)d * OUTC + j];
#pragma unroll
    for (int m = 32; m >= 1; m >>= 1) p += __shfl_xor(p, m);
    if (lane == 0) lg[j] = p + outb[j];
  }
  __syncthreads();
  if (t == 0) {
    float mx = lg[0];
    for (int j = 1; j < OUTC; j++) mx = fmaxf(mx, lg[j]);
    float se = 0.f;
    for (int j = 0; j < OUTC; j++) se += expf(lg[j] - mx);
    float lse = mx + logf(se);
    for (int j = 0; j < OUTC; j++) out[b * OUTC + j] = lg[j] - lse;
  }
}

extern "C" void kernel_launch(void* const* d_in, const int* in_sizes, int n_in,
                              void* d_out, int out_size, void* d_ws, size_t ws_size,
                              hipStream_t stream) {
  const float* attn_bias = (const float*)d_in[0];
  const float* x      = (const float*)d_in[1];
  const float* enc_W  = (const float*)d_in[2];
  const float* enc_b  = (const float*)d_in[3];
  const float* gtok   = (const float*)d_in[4];
  const float* gvd    = (const float*)d_in[5];
  const float* ln1_g  = (const float*)d_in[6];
  const float* ln1_b  = (const float*)d_in[7];
  const float* Wq     = (const float*)d_in[8];
  const float* bq     = (const float*)d_in[9];
  const float* Wk     = (const float*)d_in[10];
  const float* bk     = (const float*)d_in[11];
  const float* Wv     = (const float*)d_in[12];
  const float* bv     = (const float*)d_in[13];
  const float* Wbias  = (const float*)d_in[14];
  const float* bbias  = (const float*)d_in[15];
  const float* Wo     = (const float*)d_in[16];
  const float* bo     = (const float*)d_in[17];
  const float* ln2_g  = (const float*)d_in[18];
  const float* ln2_b  = (const float*)d_in[19];
  const float* W1     = (const float*)d_in[20];
  const float* b1     = (const float*)d_in[21];
  const float* W2     = (const float*)d_in[22];
  const float* b2     = (const float*)d_in[23];
  const float* fln_g  = (const float*)d_in[24];
  const float* fln_b  = (const float*)d_in[25];
  const float* out_W  = (const float*)d_in[26];
  const float* out_b  = (const float*)d_in[27];
  float* out = (float*)d_out;
  (void)in_sizes; (void)n_in; (void)out_size; (void)ws_size;

  char* ws = (char*)d_ws;
  size_t off = 0;
  auto alloc = [&](size_t bytes) -> char* {
    char* p = ws + off; off += (bytes + 255) & ~(size_t)255; return p;
  };
  u16* wqkvt = (u16*)alloc((size_t)LAYERS * QKVW * HDIM * 2);
  u16* wot   = (u16*)alloc((size_t)LAYERS * HDIM * HDIM * 2);
  u16* w1t   = (u16*)alloc((size_t)LAYERS * FFDIM * HDIM * 2);
  u16* w2t   = (u16*)alloc((size_t)LAYERS * HDIM * FFDIM * 2);
  u16* encwt = (u16*)alloc((size_t)HDIM * INDIM * 2);
  u16* xb    = (u16*)alloc((size_t)MROWS0 * INDIM * 2);
  float* hb  = (float*)alloc((size_t)MROWS * HDIM * 4);
  u16* yb    = (u16*)alloc((size_t)MROWS * HDIM * 2);
  u16* qkvb  = (u16*)alloc((size_t)MROWS * QKVW * 2);
  u16* ob    = (u16*)alloc((size_t)MROWS * HDIM * 2);
  u16* gb8   = (u16*)alloc((size_t)BB * SEQ * SEQ * 8 * 2);
  u16* biasb = (u16*)alloc((size_t)BB * NHEADS * SEQ * SEQ * 2);  // 77 MB, per-layer reuse
  // ffn buffer exactly aliases [qkvb|ob] (7184*2304 + 7184*768 == 7184*3072 bf16),
  // lifetime-disjoint: ffn1 writes after attention/Wo consumed qkv & o.
  u16* ffnb  = qkvb;

  // weights -> bf16 transposed (N,K)
  k_transpose_qkv<<<dim3(24, 24, 18), 256, 0, stream>>>(Wq, Wk, Wv, wqkvt);
  k_transpose_b<<<dim3(24, 24, 6), 256, 0, stream>>>(Wo, wot, HDIM, HDIM);
  k_transpose_b<<<dim3(96, 24, 6), 256, 0, stream>>>(W1, w1t, HDIM, FFDIM);
  k_transpose_b<<<dim3(24, 96, 6), 256, 0, stream>>>(W2, w2t, FFDIM, HDIM);
  k_transpose_b<<<dim3(24, 4, 1), 256, 0, stream>>>(enc_W, encwt, INDIM, HDIM);
  k_cvt<<<dim3((MROWS0 * INDIM) / 256), 256, 0, stream>>>(x, xb, MROWS0 * INDIM);
  k_gb<<<dim3(BB * SEQ), 256, 0, stream>>>(attn_bias, gvd, gb8);

  // grid size helper: NBMp (m-tiles padded to 8) x nbn, 1D
  auto ggrid = [](int M, int nbn) { int nbm = (M + 127) / 128; int nbmp = (nbm + 7) & ~7;
                                    return nbmp * nbn; };

  // node encode + graph token
  k_gemm<<<dim3(ggrid(MROWS0, 6)), 256, 0, stream>>>(xb, encwt, MROWS0, INDIM, 6, 0,
      enc_b, nullptr, nullptr, hb, nullptr);
  k_token<<<dim3(BB), 256, 0, stream>>>(gtok, hb);

  int nbias = (SEQ * SEQ + 255) / 256;
  for (int l = 0; l < LAYERS; l++) {
    k_ln<<<dim3(MROWS), 256, 0, stream>>>(hb, ln1_g + l * HDIM, ln1_b + l * HDIM, yb);
    k_gemm<<<dim3(ggrid(MROWS, 18)), 256, 0, stream>>>(yb, wqkvt + (size_t)l * QKVW * HDIM,
        MROWS, HDIM, 18, 1, bq + l * HDIM, bk + l * HDIM, bv + l * HDIM, nullptr, qkvb);
    k_bias<<<dim3(nbias, BB), 256, 0, stream>>>(gb8, Wbias + l * BDIM * NHEADS,
        bbias + l * NHEADS, biasb);
    k_attn<<<dim3(96, BB), 256, 0, stream>>>(qkvb, biasb, ob);
    k_gemm<<<dim3(ggrid(MROWS, 6)), 256, 0, stream>>>(ob, wot + (size_t)l * HDIM * HDIM,
        MROWS, HDIM, 6, 2, bo + l * HDIM, nullptr, nullptr, hb, nullptr);
    k_ln<<<dim3(MROWS), 256, 0, stream>>>(hb, ln2_g + l * HDIM, ln2_b + l * HDIM, yb);
    k_gemm<<<dim3(ggrid(MROWS, 24)), 256, 0, stream>>>(yb, w1t + (size_t)l * FFDIM * HDIM,
        MROWS, HDIM, 24, 3, b1 + l * FFDIM, nullptr, nullptr, nullptr, ffnb);
    k_gemm<<<dim3(ggrid(MROWS, 6)), 256, 0, stream>>>(ffnb, w2t + (size_t)l * HDIM * FFDIM,
        MROWS, FFDIM, 6, 4, b2 + l * HDIM, nullptr, nullptr, hb, nullptr);
  }
  k_readout<<<dim3(BB), 256, 0, stream>>>(hb, fln_g, fln_b, out_W, out_b, out);
}

// Round 5
// 2332.443 us; speedup vs baseline: 1.3533x; 1.1719x over previous
//
#include <hip/hip_runtime.h>
#include <math.h>

typedef unsigned short u16;
typedef unsigned int u32;
typedef float f32x4 __attribute__((ext_vector_type(4)));
typedef __bf16 bf16x8 __attribute__((ext_vector_type(8)));

#define LAYERS 6
#define NHEADS 12
#define INDIM 128
#define HDIM 768
#define OUTC 10
#define BDIM 8
#define FFDIM 3072
#define BB 16
#define NNODE 448
#define SEQ 449
#define DHEAD 64
#define MROWS (BB*SEQ)      // 7184
#define MROWS0 (BB*NNODE)   // 7168
#define QKVW 2304

__device__ __forceinline__ u16 f2b(float f) {
  u32 u = __float_as_uint(f);
  u32 r = (u + 0x7fffu + ((u >> 16) & 1u)) >> 16;
  return (u16)r;
}
__device__ __forceinline__ float b2f(u16 h) {
  return __uint_as_float(((u32)h) << 16);
}

// fast exact-enough erf (A&S 7.1.26, |abs err| < 1.5e-7 — far below bf16 quantum)
__device__ __forceinline__ float fast_erf(float x) {
  float ax = fabsf(x);
  float t = __builtin_amdgcn_rcpf(1.0f + 0.3275911f * ax);
  float poly = t * (0.254829592f + t * (-0.284496736f + t * (1.421413741f +
               t * (-1.453152027f + t * 1.061405429f))));
  float er = 1.0f - poly * __expf(-ax * ax);
  return copysignf(er, x);
}

// direct global->LDS DMA, 16B per lane. LDS dest = wave-uniform base + lane*16.
__device__ __forceinline__ void gload16(const u16* g, u16* l) {
  __builtin_amdgcn_global_load_lds((const __attribute__((address_space(1))) void*)g,
                                   (__attribute__((address_space(3))) void*)l,
                                   16, 0, 0);
}

// ---------------- transpose + fp32->bf16 convert: in (K,N) -> out (N,K) ----------------
__device__ __forceinline__ void tile_transpose(const float* in, u16* out, int K, int N,
                                               float (*sm)[33]) {
  int n0 = blockIdx.x * 32, k0 = blockIdx.y * 32;
  int tx = threadIdx.x & 31, ty = threadIdx.x >> 5;
#pragma unroll
  for (int r = 0; r < 4; r++)
    sm[ty + 8*r][tx] = in[(size_t)(k0 + ty + 8*r) * N + n0 + tx];
  __syncthreads();
#pragma unroll
  for (int r = 0; r < 4; r++)
    out[(size_t)(n0 + ty + 8*r) * K + k0 + tx] = f2b(sm[tx][ty + 8*r]);
}

__global__ __launch_bounds__(256) void k_transpose_b(const float* __restrict__ in,
                                                     u16* __restrict__ out, int K, int N) {
  __shared__ float sm[32][33];
  in  += (size_t)blockIdx.z * K * N;
  out += (size_t)blockIdx.z * K * N;
  tile_transpose(in, out, K, N, sm);
}

__global__ __launch_bounds__(256) void k_transpose_qkv(const float* __restrict__ Wq,
    const float* __restrict__ Wk, const float* __restrict__ Wv, u16* __restrict__ out) {
  __shared__ float sm[32][33];
  int z = blockIdx.z; int l = z / 3, m = z - 3 * l;
  const float* in = (m == 0 ? Wq : (m == 1 ? Wk : Wv)) + (size_t)l * HDIM * HDIM;
  u16* o = out + (size_t)l * QKVW * HDIM + (size_t)m * HDIM * HDIM;
  tile_transpose(in, o, HDIM, HDIM, sm);
}

__global__ __launch_bounds__(256) void k_cvt(const float* __restrict__ in,
                                             u16* __restrict__ out, int n) {
  int i = blockIdx.x * 256 + threadIdx.x;
  if (i < n) out[i] = f2b(in[i]);
}

__global__ __launch_bounds__(256) void k_token(const float* __restrict__ gt, float* __restrict__ h) {
  int b = blockIdx.x;
  for (int d = threadIdx.x; d < HDIM; d += 256)
    h[((size_t)b * SEQ + NNODE) * HDIM + d] = gt[d];
}

// ---------------- LayerNorm: h fp32 row -> y bf16 row ----------------
__global__ __launch_bounds__(256) void k_ln(const float* __restrict__ h, const float* __restrict__ g,
                                            const float* __restrict__ bta, u16* __restrict__ y) {
  int row = blockIdx.x;
  const float* x = h + (size_t)row * HDIM;
  int t = threadIdx.x;
  float v0 = x[t], v1 = x[t + 256], v2 = x[t + 512];
  float s = v0 + v1 + v2;
  float q = v0*v0 + v1*v1 + v2*v2;
#pragma unroll
  for (int m = 32; m >= 1; m >>= 1) { s += __shfl_xor(s, m); q += __shfl_xor(q, m); }
  __shared__ float ss[4], qq[4];
  int w = t >> 6;
  if ((t & 63) == 0) { ss[w] = s; qq[w] = q; }
  __syncthreads();
  s = ss[0] + ss[1] + ss[2] + ss[3];
  q = qq[0] + qq[1] + qq[2] + qq[3];
  float mean = s * (1.0f / HDIM);
  float var = q * (1.0f / HDIM) - mean * mean;
  float rs = rsqrtf(var + 1e-5f);
  u16* yr = y + (size_t)row * HDIM;
  yr[t]       = f2b((v0 - mean) * rs * g[t]       + bta[t]);
  yr[t + 256] = f2b((v1 - mean) * rs * g[t + 256] + bta[t + 256]);
  yr[t + 512] = f2b((v2 - mean) * rs * g[t + 512] + bta[t + 512]);
}

// ---------------- bf16 MFMA GEMM: C(M,N) = A(M,K) * Bt(N,K)^T ----------------
// 512-thread / 8-wave blocks on a 128x128 tile: per-wave output 64x32
// (wm=wave>>2, wn=wave&3), acc 4x2 f32x4 = 32 AGPR. 2 blocks/CU (64 KB LDS)
// now gives 16 waves/CU = 4 waves/SIMD — double the latency-hiding TLP of
// the 256-thread version at identical schedule.
// Counted-vmcnt double-buffered K-loop (T4): prologue stages tiles 0 and 1
// (8 loads in flight, 4/thread per tile); loop top waits vmcnt(4) — only
// the OLDEST 4 (current tile) — next tile's loads stay in flight across the
// barrier. Tile kt+2 staged after the read-release barrier.
// T2 both-sides chunk swizzle (chunk ^= row&7) on the GLOBAL source during
// staging and on the ds_read_b128 address -> conflict-free with linear LDS.
// mode 0: enc  -> hbuf fp32 with (b,448-node)->(b,449-row) remap, +bias0
// mode 1: qkv  -> obf bf16 stride 2304, bias = concat(bq,bk,bv)
// mode 2: Wo   -> hbuf += acc + bias0
// mode 3: ffn1 -> obf bf16 stride 3072, fast-exact GELU(acc+bias0)
// mode 4: ffn2 -> hbuf += acc + bias0
__global__ __launch_bounds__(512, 4) void k_gemm(const u16* __restrict__ A, const u16* __restrict__ Bt,
    int M, int Kd, int nbn, int mode,
    const float* __restrict__ bias0, const float* __restrict__ bias1, const float* __restrict__ bias2,
    float* __restrict__ hbuf, u16* __restrict__ obf) {
  int lin = blockIdx.x;
  int grpsz = nbn * 8;
  int grp = lin / grpsz;
  int rem = lin - grp * grpsz;
  int bn = rem >> 3;
  int bm = grp * 8 + (rem & 7);
  if (bm * 128 >= M) return;

  __shared__ __align__(16) u16 As[2][128 * 64];
  __shared__ __align__(16) u16 Bs[2][128 * 64];
  int tid = threadIdx.x;
  int lane = tid & 63, wave = tid >> 6;      // wave 0..7
  int wm = wave >> 2, wn = wave & 3;         // 2 x 4 wave grid, per-wave 64x32
  int lh = lane & 15, quad = lane >> 4;

  f32x4 zero4 = {0.f, 0.f, 0.f, 0.f};
  f32x4 acc[4][2];
#pragma unroll
  for (int i = 0; i < 4; i++)
#pragma unroll
    for (int j = 0; j < 2; j++) acc[i][j] = zero4;

  // staging map: wave w, instr r cover LDS rows [w*16+r*8, +8); lane l ->
  // row w*16+r*8+(l>>3), LDS chunk l&7, GLOBAL chunk (l&7)^(l>>3)  (row&7 == l>>3)
  int schunk = ((lane & 7) ^ (lane >> 3)) * 8;  // u16 units, 16B chunks
  const u16* pa[2];
  const u16* pb[2];
#pragma unroll
  for (int r = 0; r < 2; r++) {
    int ar = bm * 128 + wave * 16 + r * 8 + (lane >> 3);
    if (ar > M - 1) ar = M - 1;  // duplicate row; outputs masked at epilogue
    pa[r] = A + (size_t)ar * Kd + schunk;
    int br = bn * 128 + wave * 16 + r * 8 + (lane >> 3);  // N always multiple of 128
    pb[r] = Bt + (size_t)br * Kd + schunk;
  }
  int ldsb = wave * 1024;  // u16 idx: 16 rows * 64 per wave

  auto stage = [&](int bufi) {
#pragma unroll
    for (int r = 0; r < 2; r++) {
      gload16(pa[r], &As[bufi][ldsb + r * 512]);
      gload16(pb[r], &Bs[bufi][ldsb + r * 512]);
      pa[r] += 64; pb[r] += 64;
    }
  };
  auto compute = [&](int bufi) {
#pragma unroll
    for (int ks = 0; ks < 2; ks++) {
      int cs = (((ks * 4 + quad) ^ (lh & 7)) * 8);  // read-side swizzle (row&7 == lh&7)
      bf16x8 af[4], bfr[2];
#pragma unroll
      for (int mt = 0; mt < 4; mt++)
        af[mt] = *(const bf16x8*)&As[bufi][(wm * 64 + mt * 16 + lh) * 64 + cs];
#pragma unroll
      for (int nt = 0; nt < 2; nt++)
        bfr[nt] = *(const bf16x8*)&Bs[bufi][(wn * 32 + nt * 16 + lh) * 64 + cs];
#pragma unroll
      for (int mt = 0; mt < 4; mt++)
#pragma unroll
        for (int nt = 0; nt < 2; nt++)
          acc[mt][nt] = __builtin_amdgcn_mfma_f32_16x16x32_bf16(af[mt], bfr[nt], acc[mt][nt], 0, 0, 0);
    }
  };

  int kiters = Kd >> 6;  // >= 2 always (Kd: 128 / 768 / 3072)
  stage(0);              // tile 0 -> buf0 (4 loads/thread)
  stage(1);              // tile 1 -> buf1 (8 in flight)
  for (int kt = 0; kt < kiters; kt++) {
    int cur = kt & 1;
    if (kt < kiters - 1) {
      // wait only the oldest 4 loads (tile kt); tile kt+1's stay in flight
      asm volatile("s_waitcnt vmcnt(4)" ::: "memory");
    } else {
      asm volatile("s_waitcnt vmcnt(0)" ::: "memory");
    }
    __builtin_amdgcn_sched_barrier(0);
    __builtin_amdgcn_s_barrier();          // tile kt visible to all waves
    __builtin_amdgcn_sched_barrier(0);
    compute(cur);
    __builtin_amdgcn_sched_barrier(0);
    __builtin_amdgcn_s_barrier();          // all waves done reading buf[cur]
    __builtin_amdgcn_sched_barrier(0);
    if (kt + 2 < kiters) stage(cur);       // tile kt+2 -> buf[cur]
  }

#pragma unroll
  for (int mt = 0; mt < 4; mt++) {
#pragma unroll
    for (int nt = 0; nt < 2; nt++) {
      f32x4 v = acc[mt][nt];
      int gc = bn * 128 + wn * 32 + nt * 16 + lh;
#pragma unroll
      for (int r = 0; r < 4; r++) {
        int gr = bm * 128 + wm * 64 + mt * 16 + quad * 4 + r;
        if (gr >= M) continue;
        float val = v[r];
        if (mode == 0) {
          int b = gr / NNODE, sNode = gr - b * NNODE;
          hbuf[((size_t)(b * SEQ + sNode)) * HDIM + gc] = val + bias0[gc];
        } else if (mode == 1) {
          float bias = (gc < 768) ? bias0[gc] : ((gc < 1536) ? bias1[gc - 768] : bias2[gc - 1536]);
          obf[(size_t)gr * QKVW + gc] = f2b(val + bias);
        } else if (mode == 3) {
          float tt = val + bias0[gc];
          float gg = 0.5f * tt * (1.0f + fast_erf(tt * 0.70710678f));
          obf[(size_t)gr * FFDIM + gc] = f2b(gg);
        } else {  // mode 2 / 4: residual accumulate
          size_t p = (size_t)gr * HDIM + gc;
          hbuf[p] += val + bias0[gc];
        }
      }
    }
  }
}

// ---------------- one-time compact pair bias: gb8 (B,S,S,8) bf16 ----------------
__global__ __launch_bounds__(256) void k_gb(const float* __restrict__ ab,
    const float* __restrict__ gvd, u16* __restrict__ gb8) {
  int blk = blockIdx.x;               // b*SEQ + q
  int b = blk / SEQ, q = blk - b * SEQ;
  float4 gv0 = *(const float4*)gvd;
  float4 gv1 = *(const float4*)(gvd + 4);
  for (int k = threadIdx.x; k < SEQ; k += 256) {
    float4 d0, d1;
    if (q < NNODE && k < NNODE) {
      const float* src = ab + (((size_t)b * NNODE + q) * NNODE + k) * BDIM;
      d0 = *(const float4*)src; d1 = *(const float4*)(src + 4);
    } else { d0 = gv0; d1 = gv1; }
    u16 o[8] = {f2b(d0.x), f2b(d0.y), f2b(d0.z), f2b(d0.w),
                f2b(d1.x), f2b(d1.y), f2b(d1.z), f2b(d1.w)};
    *(uint4*)&gb8[((size_t)blk * SEQ + k) * 8] = *(uint4*)o;
  }
}

// ---------------- per-layer bias table: bias[b,h,q,k] = gb8[b,q,k,:].Wbias[:,h] + bbias[h] ----
__global__ __launch_bounds__(256) void k_bias(const u16* __restrict__ gb8,
    const float* __restrict__ wbias, const float* __restrict__ bbv,
    u16* __restrict__ bias) {
  int b = blockIdx.y;
  int p = blockIdx.x * 256 + threadIdx.x;   // q*SEQ + k
  if (p >= SEQ * SEQ) return;
  union { bf16x8 v; u16 u[8]; } g;
  g.v = *(const bf16x8*)(gb8 + ((size_t)b * SEQ * SEQ + p) * 8);
  float gv[8];
#pragma unroll
  for (int d = 0; d < 8; d++) gv[d] = b2f(g.u[d]);
#pragma unroll
  for (int h = 0; h < NHEADS; h++) {
    float s = bbv[h];
#pragma unroll
    for (int d = 0; d < 8; d++) s = fmaf(gv[d], wbias[d * NHEADS + h], s);
    bias[(size_t)(b * NHEADS + h) * SEQ * SEQ + p] = f2b(s);
  }
}

// ---------------- flash attention, bias from precomputed table ----------------
__global__ __launch_bounds__(256) void k_attn(const u16* __restrict__ qkv,
    const u16* __restrict__ bias, u16* __restrict__ obf) {
  int head = blockIdx.x % 12, qt = blockIdx.x / 12;
  int b = blockIdx.y;
  int wave = threadIdx.x >> 6, lane = threadIdx.x & 63;
  int tid = threadIdx.x;
  int lh = lane & 15, quad = lane >> 4;
  int q0 = qt * 64 + wave * 16;

  __shared__ __align__(16) u16 P[4][16 * 32];
  __shared__ __align__(16) u16 Vt[64 * 40];  // [d][swizzled key] stride 40

  const u16* Qb = qkv + head * DHEAD;
  const u16* Kb = qkv + 768 + head * DHEAD;
  const u16* Vb = qkv + 1536 + head * DHEAD;
  const u16* bias_b = bias + (size_t)(b * NHEADS + head) * SEQ * SEQ;

  int qr = q0 + lh; if (qr > NNODE) qr = NNODE;
  size_t qrow = ((size_t)b * SEQ + qr) * QKVW;
  bf16x8 aq0 = *(const bf16x8*)(Qb + qrow + quad * 8);
  bf16x8 aq1 = *(const bf16x8*)(Qb + qrow + 32 + quad * 8);

  // V staging map: thread t -> key kbase+(t>>3), dims (t&7)*8 .. +8
  int vkid = tid >> 3;          // key within chunk tile (0..31)
  int vd0 = (tid & 7) * 8;      // d base (0..56)
  int vcc = (((vkid >> 3) ^ ((vd0 >> 3) & 3)) << 3) | (vkid & 7);

  f32x4 zero4 = {0.f, 0.f, 0.f, 0.f};
  float mrun[4], lrun[4];
  f32x4 acc[4];
#pragma unroll
  for (int r = 0; r < 4; r++) { mrun[r] = -3.0e38f; lrun[r] = 0.f; }
#pragma unroll
  for (int nt = 0; nt < 4; nt++) acc[nt] = zero4;

  int qrow_r[4];
#pragma unroll
  for (int r = 0; r < 4; r++) {
    int qq = q0 + quad * 4 + r; if (qq > NNODE) qq = NNODE;
    qrow_r[r] = qq;
  }

  for (int kc = 0; kc < 15; kc++) {
    int kbase = kc * 32;
    int key0 = kbase + lh;      if (key0 > NNODE) key0 = NNODE;
    int key1 = kbase + 16 + lh; if (key1 > NNODE) key1 = NNODE;
    size_t kr0 = ((size_t)b * SEQ + key0) * QKVW;
    size_t kr1 = ((size_t)b * SEQ + key1) * QKVW;
    bf16x8 bk00 = *(const bf16x8*)(Kb + kr0 + quad * 8);
    bf16x8 bk01 = *(const bf16x8*)(Kb + kr0 + 32 + quad * 8);
    bf16x8 bk10 = *(const bf16x8*)(Kb + kr1 + quad * 8);
    bf16x8 bk11 = *(const bf16x8*)(Kb + kr1 + 32 + quad * 8);

    // issue V tile load early; consumed at the LDS write after the barrier
    int vkey = kbase + vkid; if (vkey > NNODE) vkey = NNODE;
    union { bf16x8 v; u16 u[8]; } vst;
    vst.v = *(const bf16x8*)(Vb + ((size_t)b * SEQ + vkey) * QKVW + vd0);

    // bias reads (2B each, coalesced within 16-lane groups)
    float bi0[4], bi1[4];
#pragma unroll
    for (int r = 0; r < 4; r++) {
      const u16* br_ = bias_b + (size_t)qrow_r[r] * SEQ;
      bi0[r] = b2f(br_[key0]);
      bi1[r] = b2f(br_[key1]);
    }

    f32x4 s0 = __builtin_amdgcn_mfma_f32_16x16x32_bf16(aq0, bk00, zero4, 0, 0, 0);
    s0 = __builtin_amdgcn_mfma_f32_16x16x32_bf16(aq1, bk01, s0, 0, 0, 0);
    f32x4 s1 = __builtin_amdgcn_mfma_f32_16x16x32_bf16(aq0, bk10, zero4, 0, 0, 0);
    s1 = __builtin_amdgcn_mfma_f32_16x16x32_bf16(aq1, bk11, s1, 0, 0, 0);

    int k0c = kbase + lh, k1c = kbase + 16 + lh;
    float sv0[4], sv1[4];
#pragma unroll
    for (int r = 0; r < 4; r++) {
      sv0[r] = (k0c < SEQ) ? fmaf(s0[r], 0.125f, bi0[r]) : -1e30f;
      sv1[r] = (k1c < SEQ) ? fmaf(s1[r], 0.125f, bi1[r]) : -1e30f;
    }
    float tm[4];
#pragma unroll
    for (int r = 0; r < 4; r++) tm[r] = fmaxf(sv0[r], sv1[r]);
#pragma unroll
    for (int m = 1; m <= 8; m <<= 1)
#pragma unroll
      for (int r = 0; r < 4; r++) tm[r] = fmaxf(tm[r], __shfl_xor(tm[r], m));
    float alpha[4];
#pragma unroll
    for (int r = 0; r < 4; r++) {
      float mnew = fmaxf(mrun[r], tm[r]);
      alpha[r] = __expf(mrun[r] - mnew);
      mrun[r] = mnew;
    }
    float p0[4], p1[4], rsum[4];
#pragma unroll
    for (int r = 0; r < 4; r++) {
      p0[r] = __expf(sv0[r] - mrun[r]);
      p1[r] = __expf(sv1[r] - mrun[r]);
      rsum[r] = p0[r] + p1[r];
    }
#pragma unroll
    for (int m = 1; m <= 8; m <<= 1)
#pragma unroll
      for (int r = 0; r < 4; r++) rsum[r] += __shfl_xor(rsum[r], m);
#pragma unroll
    for (int r = 0; r < 4; r++) lrun[r] = lrun[r] * alpha[r] + rsum[r];
#pragma unroll
    for (int nt = 0; nt < 4; nt++)
#pragma unroll
      for (int r = 0; r < 4; r++) acc[nt][r] *= alpha[r];

    __syncthreads();  // previous iter's P/Vt reads complete
    u16* pw = &P[wave][0];
#pragma unroll
    for (int r = 0; r < 4; r++) {
      int prow = quad * 4 + r;
      pw[prow * 32 + lh]      = f2b(p0[r]);
      pw[prow * 32 + 16 + lh] = f2b(p1[r]);
    }
#pragma unroll
    for (int j = 0; j < 8; j++) Vt[(vd0 + j) * 40 + vcc] = vst.u[j];
    __syncthreads();  // P + Vt visible
    bf16x8 ap = *(const bf16x8*)&P[wave][lh * 32 + quad * 8];

#pragma unroll
    for (int nt = 0; nt < 4; nt++) {
      int d = nt * 16 + lh;
      int rc = (quad ^ ((d >> 3) & 3)) << 3;   // read-side key-chunk swizzle
      bf16x8 vb = *(const bf16x8*)&Vt[d * 40 + rc];
      acc[nt] = __builtin_amdgcn_mfma_f32_16x16x32_bf16(ap, vb, acc[nt], 0, 0, 0);
    }
  }

#pragma unroll
  for (int nt = 0; nt < 4; nt++)
#pragma unroll
    for (int r = 0; r < 4; r++) {
      int qq = q0 + quad * 4 + r;
      if (qq < SEQ) {
        float o = acc[nt][r] / lrun[r];
        obf[((size_t)b * SEQ + qq) * HDIM + head * DHEAD + nt * 16 + lh] = f2b(o);
      }
    }
}

// ---------------- final LN + readout + log_softmax ----------------
__global__ __launch_bounds__(256) void k_readout(const float* __restrict__ h,
    const float* __restrict__ fg, const float* __restrict__ fb,
    const float* __restrict__ outW, const float* __restrict__ outb, float* __restrict__ out) {
  int b = blockIdx.x;
  const float* x = h + (size_t)b * SEQ * HDIM;  // node 0 row
  int t = threadIdx.x;
  float v0 = x[t], v1 = x[t + 256], v2 = x[t + 512];
  float s = v0 + v1 + v2, q = v0*v0 + v1*v1 + v2*v2;
#pragma unroll
  for (int m = 32; m >= 1; m >>= 1) { s += __shfl_xor(s, m); q += __shfl_xor(q, m); }
  __shared__ float ss[4], qq[4];
  int w = t >> 6, lane = t & 63;
  if (lane == 0) { ss[w] = s; qq[w] = q; }
  __syncthreads();
  s = ss[0] + ss[1] + ss[2] + ss[3];
  q = qq[0] + qq[1] + qq[2] + qq[3];
  float mean = s * (1.0f / HDIM);
  float var = q * (1.0f / HDIM) - mean * mean;
  float rs = rsqrtf(var + 1e-5f);
  __shared__ float yn[HDIM];
  yn[t]       = (v0 - mean) * rs * fg[t]       + fb[t];
  yn[t + 256] = (v1 - mean) * rs * fg[t + 256] + fb[t + 256];
  yn[t + 512] = (v2 - mean) * rs * fg[t + 512] + fb[t + 512];
  __syncthreads();
  __shared__ float lg[OUTC];
  for (int j = w; j < OUTC; j += 4) {
    float p = 0.f;
    for (int d = lane; d < HDIM; d += 64) p += yn[d] * outW[(size_t)d * OUTC + j];
#pragma unroll
    for (int m = 32; m >= 1; m >>= 1) p += __shfl_xor(p, m);
    if (lane == 0) lg[j] = p + outb[j];
  }
  __syncthreads();
  if (t == 0) {
    float mx = lg[0];
    for (int j = 1; j < OUTC; j++) mx = fmaxf(mx, lg[j]);
    float se = 0.f;
    for (int j = 0; j < OUTC; j++) se += expf(lg[j] - mx);
    float lse = mx + logf(se);
    for (int j = 0; j < OUTC; j++) out[b * OUTC + j] = lg[j] - lse;
  }
}

extern "C" void kernel_launch(void* const* d_in, const int* in_sizes, int n_in,
                              void* d_out, int out_size, void* d_ws, size_t ws_size,
                              hipStream_t stream) {
  const float* attn_bias = (const float*)d_in[0];
  const float* x      = (const float*)d_in[1];
  const float* enc_W  = (const float*)d_in[2];
  const float* enc_b  = (const float*)d_in[3];
  const float* gtok   = (const float*)d_in[4];
  const float* gvd    = (const float*)d_in[5];
  const float* ln1_g  = (const float*)d_in[6];
  const float* ln1_b  = (const float*)d_in[7];
  const float* Wq     = (const float*)d_in[8];
  const float* bq     = (const float*)d_in[9];
  const float* Wk     = (const float*)d_in[10];
  const float* bk     = (const float*)d_in[11];
  const float* Wv     = (const float*)d_in[12];
  const float* bv     = (const float*)d_in[13];
  const float* Wbias  = (const float*)d_in[14];
  const float* bbias  = (const float*)d_in[15];
  const float* Wo     = (const float*)d_in[16];
  const float* bo     = (const float*)d_in[17];
  const float* ln2_g  = (const float*)d_in[18];
  const float* ln2_b  = (const float*)d_in[19];
  const float* W1     = (const float*)d_in[20];
  const float* b1     = (const float*)d_in[21];
  const float* W2     = (const float*)d_in[22];
  const float* b2     = (const float*)d_in[23];
  const float* fln_g  = (const float*)d_in[24];
  const float* fln_b  = (const float*)d_in[25];
  const float* out_W  = (const float*)d_in[26];
  const float* out_b  = (const float*)d_in[27];
  float* out = (float*)d_out;
  (void)in_sizes; (void)n_in; (void)out_size; (void)ws_size;

  char* ws = (char*)d_ws;
  size_t off = 0;
  auto alloc = [&](size_t bytes) -> char* {
    char* p = ws + off; off += (bytes + 255) & ~(size_t)255; return p;
  };
  u16* wqkvt = (u16*)alloc((size_t)LAYERS * QKVW * HDIM * 2);
  u16* wot   = (u16*)alloc((size_t)LAYERS * HDIM * HDIM * 2);
  u16* w1t   = (u16*)alloc((size_t)LAYERS * FFDIM * HDIM * 2);
  u16* w2t   = (u16*)alloc((size_t)LAYERS * HDIM * FFDIM * 2);
  u16* encwt = (u16*)alloc((size_t)HDIM * INDIM * 2);
  u16* xb    = (u16*)alloc((size_t)MROWS0 * INDIM * 2);
  float* hb  = (float*)alloc((size_t)MROWS * HDIM * 4);
  u16* yb    = (u16*)alloc((size_t)MROWS * HDIM * 2);
  u16* qkvb  = (u16*)alloc((size_t)MROWS * QKVW * 2);
  u16* ob    = (u16*)alloc((size_t)MROWS * HDIM * 2);
  u16* gb8   = (u16*)alloc((size_t)BB * SEQ * SEQ * 8 * 2);
  u16* biasb = (u16*)alloc((size_t)BB * NHEADS * SEQ * SEQ * 2);  // 77 MB, per-layer reuse
  // ffn buffer exactly aliases [qkvb|ob] (7184*2304 + 7184*768 == 7184*3072 bf16),
  // lifetime-disjoint: ffn1 writes after attention/Wo consumed qkv & o.
  u16* ffnb  = qkvb;

  // weights -> bf16 transposed (N,K)
  k_transpose_qkv<<<dim3(24, 24, 18), 256, 0, stream>>>(Wq, Wk, Wv, wqkvt);
  k_transpose_b<<<dim3(24, 24, 6), 256, 0, stream>>>(Wo, wot, HDIM, HDIM);
  k_transpose_b<<<dim3(96, 24, 6), 256, 0, stream>>>(W1, w1t, HDIM, FFDIM);
  k_transpose_b<<<dim3(24, 96, 6), 256, 0, stream>>>(W2, w2t, FFDIM, HDIM);
  k_transpose_b<<<dim3(24, 4, 1), 256, 0, stream>>>(enc_W, encwt, INDIM, HDIM);
  k_cvt<<<dim3((MROWS0 * INDIM) / 256), 256, 0, stream>>>(x, xb, MROWS0 * INDIM);
  k_gb<<<dim3(BB * SEQ), 256, 0, stream>>>(attn_bias, gvd, gb8);

  // grid size helper: NBMp (m-tiles padded to 8) x nbn, 1D
  auto ggrid = [](int M, int nbn) { int nbm = (M + 127) / 128; int nbmp = (nbm + 7) & ~7;
                                    return nbmp * nbn; };

  // node encode + graph token
  k_gemm<<<dim3(ggrid(MROWS0, 6)), 512, 0, stream>>>(xb, encwt, MROWS0, INDIM, 6, 0,
      enc_b, nullptr, nullptr, hb, nullptr);
  k_token<<<dim3(BB), 256, 0, stream>>>(gtok, hb);

  int nbias = (SEQ * SEQ + 255) / 256;
  for (int l = 0; l < LAYERS; l++) {
    k_ln<<<dim3(MROWS), 256, 0, stream>>>(hb, ln1_g + l * HDIM, ln1_b + l * HDIM, yb);
    k_gemm<<<dim3(ggrid(MROWS, 18)), 512, 0, stream>>>(yb, wqkvt + (size_t)l * QKVW * HDIM,
        MROWS, HDIM, 18, 1, bq + l * HDIM, bk + l * HDIM, bv + l * HDIM, nullptr, qkvb);
    k_bias<<<dim3(nbias, BB), 256, 0, stream>>>(gb8, Wbias + l * BDIM * NHEADS,
        bbias + l * NHEADS, biasb);
    k_attn<<<dim3(96, BB), 256, 0, stream>>>(qkvb, biasb, ob);
    k_gemm<<<dim3(ggrid(MROWS, 6)), 512, 0, stream>>>(ob, wot + (size_t)l * HDIM * HDIM,
        MROWS, HDIM, 6, 2, bo + l * HDIM, nullptr, nullptr, hb, nullptr);
    k_ln<<<dim3(MROWS), 256, 0, stream>>>(hb, ln2_g + l * HDIM, ln2_b + l * HDIM, yb);
    k_gemm<<<dim3(ggrid(MROWS, 24)), 512, 0, stream>>>(yb, w1t + (size_t)l * FFDIM * HDIM,
        MROWS, HDIM, 24, 3, b1 + l * FFDIM, nullptr, nullptr, nullptr, ffnb);
    k_gemm<<<dim3(ggrid(MROWS, 6)), 512, 0, stream>>>(ffnb, w2t + (size_t)l * HDIM * FFDIM,
        MROWS, FFDIM, 6, 4, b2 + l * HDIM, nullptr, nullptr, hb, nullptr);
  }
  k_readout<<<dim3(BB), 256, 0, stream>>>(hb, fln_g, fln_b, out_W, out_b, out);
}

// Round 6
// 2322.449 us; speedup vs baseline: 1.3592x; 1.0043x over previous
//
#include <hip/hip_runtime.h>
#include <math.h>

typedef unsigned short u16;
typedef unsigned int u32;
typedef float f32x4 __attribute__((ext_vector_type(4)));
typedef __bf16 bf16x8 __attribute__((ext_vector_type(8)));

#define LAYERS 6
#define NHEADS 12
#define INDIM 128
#define HDIM 768
#define OUTC 10
#define BDIM 8
#define FFDIM 3072
#define BB 16
#define NNODE 448
#define SEQ 449
#define DHEAD 64
#define MROWS (BB*SEQ)      // 7184
#define MROWS0 (BB*NNODE)   // 7168
#define QKVW 2304

__device__ __forceinline__ u16 f2b(float f) {
  u32 u = __float_as_uint(f);
  u32 r = (u + 0x7fffu + ((u >> 16) & 1u)) >> 16;
  return (u16)r;
}
__device__ __forceinline__ float b2f(u16 h) {
  return __uint_as_float(((u32)h) << 16);
}

// fast exact-enough erf (A&S 7.1.26, |abs err| < 1.5e-7 — far below bf16 quantum)
__device__ __forceinline__ float fast_erf(float x) {
  float ax = fabsf(x);
  float t = __builtin_amdgcn_rcpf(1.0f + 0.3275911f * ax);
  float poly = t * (0.254829592f + t * (-0.284496736f + t * (1.421413741f +
               t * (-1.453152027f + t * 1.061405429f))));
  float er = 1.0f - poly * __expf(-ax * ax);
  return copysignf(er, x);
}

// direct global->LDS DMA, 16B per lane. LDS dest = wave-uniform base + lane*16.
__device__ __forceinline__ void gload16(const u16* g, u16* l) {
  __builtin_amdgcn_global_load_lds((const __attribute__((address_space(1))) void*)g,
                                   (__attribute__((address_space(3))) void*)l,
                                   16, 0, 0);
}

// ---------------- transpose + fp32->bf16 convert: in (K,N) -> out (N,K) ----------------
__device__ __forceinline__ void tile_transpose(const float* in, u16* out, int K, int N,
                                               float (*sm)[33]) {
  int n0 = blockIdx.x * 32, k0 = blockIdx.y * 32;
  int tx = threadIdx.x & 31, ty = threadIdx.x >> 5;
#pragma unroll
  for (int r = 0; r < 4; r++)
    sm[ty + 8*r][tx] = in[(size_t)(k0 + ty + 8*r) * N + n0 + tx];
  __syncthreads();
#pragma unroll
  for (int r = 0; r < 4; r++)
    out[(size_t)(n0 + ty + 8*r) * K + k0 + tx] = f2b(sm[tx][ty + 8*r]);
}

__global__ __launch_bounds__(256) void k_transpose_b(const float* __restrict__ in,
                                                     u16* __restrict__ out, int K, int N) {
  __shared__ float sm[32][33];
  in  += (size_t)blockIdx.z * K * N;
  out += (size_t)blockIdx.z * K * N;
  tile_transpose(in, out, K, N, sm);
}

__global__ __launch_bounds__(256) void k_transpose_qkv(const float* __restrict__ Wq,
    const float* __restrict__ Wk, const float* __restrict__ Wv, u16* __restrict__ out) {
  __shared__ float sm[32][33];
  int z = blockIdx.z; int l = z / 3, m = z - 3 * l;
  const float* in = (m == 0 ? Wq : (m == 1 ? Wk : Wv)) + (size_t)l * HDIM * HDIM;
  u16* o = out + (size_t)l * QKVW * HDIM + (size_t)m * HDIM * HDIM;
  tile_transpose(in, o, HDIM, HDIM, sm);
}

__global__ __launch_bounds__(256) void k_cvt(const float* __restrict__ in,
                                             u16* __restrict__ out, int n) {
  int i = blockIdx.x * 256 + threadIdx.x;
  if (i < n) out[i] = f2b(in[i]);
}

__global__ __launch_bounds__(256) void k_token(const float* __restrict__ gt, float* __restrict__ h) {
  int b = blockIdx.x;
  for (int d = threadIdx.x; d < HDIM; d += 256)
    h[((size_t)b * SEQ + NNODE) * HDIM + d] = gt[d];
}

// ---------------- LayerNorm: h fp32 row -> y bf16 row ----------------
__global__ __launch_bounds__(256) void k_ln(const float* __restrict__ h, const float* __restrict__ g,
                                            const float* __restrict__ bta, u16* __restrict__ y) {
  int row = blockIdx.x;
  const float* x = h + (size_t)row * HDIM;
  int t = threadIdx.x;
  float v0 = x[t], v1 = x[t + 256], v2 = x[t + 512];
  float s = v0 + v1 + v2;
  float q = v0*v0 + v1*v1 + v2*v2;
#pragma unroll
  for (int m = 32; m >= 1; m >>= 1) { s += __shfl_xor(s, m); q += __shfl_xor(q, m); }
  __shared__ float ss[4], qq[4];
  int w = t >> 6;
  if ((t & 63) == 0) { ss[w] = s; qq[w] = q; }
  __syncthreads();
  s = ss[0] + ss[1] + ss[2] + ss[3];
  q = qq[0] + qq[1] + qq[2] + qq[3];
  float mean = s * (1.0f / HDIM);
  float var = q * (1.0f / HDIM) - mean * mean;
  float rs = rsqrtf(var + 1e-5f);
  u16* yr = y + (size_t)row * HDIM;
  yr[t]       = f2b((v0 - mean) * rs * g[t]       + bta[t]);
  yr[t + 256] = f2b((v1 - mean) * rs * g[t + 256] + bta[t + 256]);
  yr[t + 512] = f2b((v2 - mean) * rs * g[t + 512] + bta[t + 512]);
}

// ---------------- bf16 MFMA GEMM: C(M,N) = A(M,K) * Bt(N,K)^T ----------------
// 512-thread / 8-wave blocks on a 128x128 tile, counted-vmcnt double-buffered
// K-loop (see round-4/5 notes). T2 both-sides chunk swizzle on staging source
// and ds_read address.
__global__ __launch_bounds__(512, 4) void k_gemm(const u16* __restrict__ A, const u16* __restrict__ Bt,
    int M, int Kd, int nbn, int mode,
    const float* __restrict__ bias0, const float* __restrict__ bias1, const float* __restrict__ bias2,
    float* __restrict__ hbuf, u16* __restrict__ obf) {
  int lin = blockIdx.x;
  int grpsz = nbn * 8;
  int grp = lin / grpsz;
  int rem = lin - grp * grpsz;
  int bn = rem >> 3;
  int bm = grp * 8 + (rem & 7);
  if (bm * 128 >= M) return;

  __shared__ __align__(16) u16 As[2][128 * 64];
  __shared__ __align__(16) u16 Bs[2][128 * 64];
  int tid = threadIdx.x;
  int lane = tid & 63, wave = tid >> 6;      // wave 0..7
  int wm = wave >> 2, wn = wave & 3;         // 2 x 4 wave grid, per-wave 64x32
  int lh = lane & 15, quad = lane >> 4;

  f32x4 zero4 = {0.f, 0.f, 0.f, 0.f};
  f32x4 acc[4][2];
#pragma unroll
  for (int i = 0; i < 4; i++)
#pragma unroll
    for (int j = 0; j < 2; j++) acc[i][j] = zero4;

  int schunk = ((lane & 7) ^ (lane >> 3)) * 8;  // u16 units, 16B chunks
  const u16* pa[2];
  const u16* pb[2];
#pragma unroll
  for (int r = 0; r < 2; r++) {
    int ar = bm * 128 + wave * 16 + r * 8 + (lane >> 3);
    if (ar > M - 1) ar = M - 1;  // duplicate row; outputs masked at epilogue
    pa[r] = A + (size_t)ar * Kd + schunk;
    int br = bn * 128 + wave * 16 + r * 8 + (lane >> 3);  // N always multiple of 128
    pb[r] = Bt + (size_t)br * Kd + schunk;
  }
  int ldsb = wave * 1024;  // u16 idx: 16 rows * 64 per wave

  auto stage = [&](int bufi) {
#pragma unroll
    for (int r = 0; r < 2; r++) {
      gload16(pa[r], &As[bufi][ldsb + r * 512]);
      gload16(pb[r], &Bs[bufi][ldsb + r * 512]);
      pa[r] += 64; pb[r] += 64;
    }
  };
  auto compute = [&](int bufi) {
#pragma unroll
    for (int ks = 0; ks < 2; ks++) {
      int cs = (((ks * 4 + quad) ^ (lh & 7)) * 8);  // read-side swizzle (row&7 == lh&7)
      bf16x8 af[4], bfr[2];
#pragma unroll
      for (int mt = 0; mt < 4; mt++)
        af[mt] = *(const bf16x8*)&As[bufi][(wm * 64 + mt * 16 + lh) * 64 + cs];
#pragma unroll
      for (int nt = 0; nt < 2; nt++)
        bfr[nt] = *(const bf16x8*)&Bs[bufi][(wn * 32 + nt * 16 + lh) * 64 + cs];
#pragma unroll
      for (int mt = 0; mt < 4; mt++)
#pragma unroll
        for (int nt = 0; nt < 2; nt++)
          acc[mt][nt] = __builtin_amdgcn_mfma_f32_16x16x32_bf16(af[mt], bfr[nt], acc[mt][nt], 0, 0, 0);
    }
  };

  int kiters = Kd >> 6;  // >= 2 always (Kd: 128 / 768 / 3072)
  stage(0);              // tile 0 -> buf0 (4 loads/thread)
  stage(1);              // tile 1 -> buf1 (8 in flight)
  for (int kt = 0; kt < kiters; kt++) {
    int cur = kt & 1;
    if (kt < kiters - 1) {
      asm volatile("s_waitcnt vmcnt(4)" ::: "memory");
    } else {
      asm volatile("s_waitcnt vmcnt(0)" ::: "memory");
    }
    __builtin_amdgcn_sched_barrier(0);
    __builtin_amdgcn_s_barrier();          // tile kt visible to all waves
    __builtin_amdgcn_sched_barrier(0);
    compute(cur);
    __builtin_amdgcn_sched_barrier(0);
    __builtin_amdgcn_s_barrier();          // all waves done reading buf[cur]
    __builtin_amdgcn_sched_barrier(0);
    if (kt + 2 < kiters) stage(cur);       // tile kt+2 -> buf[cur]
  }

#pragma unroll
  for (int mt = 0; mt < 4; mt++) {
#pragma unroll
    for (int nt = 0; nt < 2; nt++) {
      f32x4 v = acc[mt][nt];
      int gc = bn * 128 + wn * 32 + nt * 16 + lh;
#pragma unroll
      for (int r = 0; r < 4; r++) {
        int gr = bm * 128 + wm * 64 + mt * 16 + quad * 4 + r;
        if (gr >= M) continue;
        float val = v[r];
        if (mode == 0) {
          int b = gr / NNODE, sNode = gr - b * NNODE;
          hbuf[((size_t)(b * SEQ + sNode)) * HDIM + gc] = val + bias0[gc];
        } else if (mode == 1) {
          float bias = (gc < 768) ? bias0[gc] : ((gc < 1536) ? bias1[gc - 768] : bias2[gc - 1536]);
          obf[(size_t)gr * QKVW + gc] = f2b(val + bias);
        } else if (mode == 3) {
          float tt = val + bias0[gc];
          float gg = 0.5f * tt * (1.0f + fast_erf(tt * 0.70710678f));
          obf[(size_t)gr * FFDIM + gc] = f2b(gg);
        } else {  // mode 2 / 4: residual accumulate
          size_t p = (size_t)gr * HDIM + gc;
          hbuf[p] += val + bias0[gc];
        }
      }
    }
  }
}

// ---------------- one-time compact pair bias: gb8 (B,S,S,8) bf16 ----------------
__global__ __launch_bounds__(256) void k_gb(const float* __restrict__ ab,
    const float* __restrict__ gvd, u16* __restrict__ gb8) {
  int blk = blockIdx.x;               // b*SEQ + q
  int b = blk / SEQ, q = blk - b * SEQ;
  float4 gv0 = *(const float4*)gvd;
  float4 gv1 = *(const float4*)(gvd + 4);
  for (int k = threadIdx.x; k < SEQ; k += 256) {
    float4 d0, d1;
    if (q < NNODE && k < NNODE) {
      const float* src = ab + (((size_t)b * NNODE + q) * NNODE + k) * BDIM;
      d0 = *(const float4*)src; d1 = *(const float4*)(src + 4);
    } else { d0 = gv0; d1 = gv1; }
    u16 o[8] = {f2b(d0.x), f2b(d0.y), f2b(d0.z), f2b(d0.w),
                f2b(d1.x), f2b(d1.y), f2b(d1.z), f2b(d1.w)};
    *(uint4*)&gb8[((size_t)blk * SEQ + k) * 8] = *(uint4*)o;
  }
}

// ---------------- per-layer bias table: bias[b,h,q,k] = gb8[b,q,k,:].Wbias[:,h] + bbias[h] ----
__global__ __launch_bounds__(256) void k_bias(const u16* __restrict__ gb8,
    const float* __restrict__ wbias, const float* __restrict__ bbv,
    u16* __restrict__ bias) {
  int b = blockIdx.y;
  int p = blockIdx.x * 256 + threadIdx.x;   // q*SEQ + k
  if (p >= SEQ * SEQ) return;
  union { bf16x8 v; u16 u[8]; } g;
  g.v = *(const bf16x8*)(gb8 + ((size_t)b * SEQ * SEQ + p) * 8);
  float gv[8];
#pragma unroll
  for (int d = 0; d < 8; d++) gv[d] = b2f(g.u[d]);
#pragma unroll
  for (int h = 0; h < NHEADS; h++) {
    float s = bbv[h];
#pragma unroll
    for (int d = 0; d < 8; d++) s = fmaf(gv[d], wbias[d * NHEADS + h], s);
    bias[(size_t)(b * NHEADS + h) * SEQ * SEQ + p] = f2b(s);
  }
}

// ---------------- flash attention, bias from precomputed table ----------------
// T13 defer-max softmax: mrun starts at 0 and is only raised (full shuffle-max
// + rescale of acc/lsum) when any lane's new score exceeds mrun+8 — never for
// this data scale (scores ~ +-0.3), so the steady-state loop has ZERO cross-
// lane shuffles. Row sum is accumulated PER LANE (lsum) and reduced once after
// the kc loop. exp values bounded by e^8 before a rescale triggers; softmax is
// shift-invariant so results are exact either way.
// P row stride 40 u16 (was 32): quad rows land 80 dwords apart == 16 mod 32,
// killing the 4-way P-write bank conflict (2-way is free). Read base
// lh*80B + quad*16B stays 16B-aligned for ds_read_b128.
__global__ __launch_bounds__(256) void k_attn(const u16* __restrict__ qkv,
    const u16* __restrict__ bias, u16* __restrict__ obf) {
  int head = blockIdx.x % 12, qt = blockIdx.x / 12;
  int b = blockIdx.y;
  int wave = threadIdx.x >> 6, lane = threadIdx.x & 63;
  int tid = threadIdx.x;
  int lh = lane & 15, quad = lane >> 4;
  int q0 = qt * 64 + wave * 16;

  __shared__ __align__(16) u16 P[4][16 * 40];  // stride 40 (see header comment)
  __shared__ __align__(16) u16 Vt[64 * 40];    // [d][swizzled key] stride 40

  const u16* Qb = qkv + head * DHEAD;
  const u16* Kb = qkv + 768 + head * DHEAD;
  const u16* Vb = qkv + 1536 + head * DHEAD;
  const u16* bias_b = bias + (size_t)(b * NHEADS + head) * SEQ * SEQ;

  int qr = q0 + lh; if (qr > NNODE) qr = NNODE;
  size_t qrow = ((size_t)b * SEQ + qr) * QKVW;
  bf16x8 aq0 = *(const bf16x8*)(Qb + qrow + quad * 8);
  bf16x8 aq1 = *(const bf16x8*)(Qb + qrow + 32 + quad * 8);

  // V staging map: thread t -> key kbase+(t>>3), dims (t&7)*8 .. +8
  int vkid = tid >> 3;          // key within chunk tile (0..31)
  int vd0 = (tid & 7) * 8;      // d base (0..56)
  int vcc = (((vkid >> 3) ^ ((vd0 >> 3) & 3)) << 3) | (vkid & 7);

  f32x4 zero4 = {0.f, 0.f, 0.f, 0.f};
  float mrun[4], lsum[4];
  f32x4 acc[4];
#pragma unroll
  for (int r = 0; r < 4; r++) { mrun[r] = 0.f; lsum[r] = 0.f; }
#pragma unroll
  for (int nt = 0; nt < 4; nt++) acc[nt] = zero4;

  int qrow_r[4];
#pragma unroll
  for (int r = 0; r < 4; r++) {
    int qq = q0 + quad * 4 + r; if (qq > NNODE) qq = NNODE;
    qrow_r[r] = qq;
  }

  for (int kc = 0; kc < 15; kc++) {
    int kbase = kc * 32;
    int key0 = kbase + lh;      if (key0 > NNODE) key0 = NNODE;
    int key1 = kbase + 16 + lh; if (key1 > NNODE) key1 = NNODE;
    size_t kr0 = ((size_t)b * SEQ + key0) * QKVW;
    size_t kr1 = ((size_t)b * SEQ + key1) * QKVW;
    bf16x8 bk00 = *(const bf16x8*)(Kb + kr0 + quad * 8);
    bf16x8 bk01 = *(const bf16x8*)(Kb + kr0 + 32 + quad * 8);
    bf16x8 bk10 = *(const bf16x8*)(Kb + kr1 + quad * 8);
    bf16x8 bk11 = *(const bf16x8*)(Kb + kr1 + 32 + quad * 8);

    // issue V tile load early; consumed at the LDS write after the barrier
    int vkey = kbase + vkid; if (vkey > NNODE) vkey = NNODE;
    union { bf16x8 v; u16 u[8]; } vst;
    vst.v = *(const bf16x8*)(Vb + ((size_t)b * SEQ + vkey) * QKVW + vd0);

    // bias reads (2B each, coalesced within 16-lane groups)
    float bi0[4], bi1[4];
#pragma unroll
    for (int r = 0; r < 4; r++) {
      const u16* br_ = bias_b + (size_t)qrow_r[r] * SEQ;
      bi0[r] = b2f(br_[key0]);
      bi1[r] = b2f(br_[key1]);
    }

    f32x4 s0 = __builtin_amdgcn_mfma_f32_16x16x32_bf16(aq0, bk00, zero4, 0, 0, 0);
    s0 = __builtin_amdgcn_mfma_f32_16x16x32_bf16(aq1, bk01, s0, 0, 0, 0);
    f32x4 s1 = __builtin_amdgcn_mfma_f32_16x16x32_bf16(aq0, bk10, zero4, 0, 0, 0);
    s1 = __builtin_amdgcn_mfma_f32_16x16x32_bf16(aq1, bk11, s1, 0, 0, 0);

    int k0c = kbase + lh, k1c = kbase + 16 + lh;
    float sv0[4], sv1[4];
#pragma unroll
    for (int r = 0; r < 4; r++) {
      sv0[r] = (k0c < SEQ) ? fmaf(s0[r], 0.125f, bi0[r]) : -1e30f;
      sv1[r] = (k1c < SEQ) ? fmaf(s1[r], 0.125f, bi1[r]) : -1e30f;
    }

    // ---- defer-max online softmax (no shuffles in the common path) ----
    float pmax[4];
#pragma unroll
    for (int r = 0; r < 4; r++) pmax[r] = fmaxf(sv0[r], sv1[r]);
    bool need = false;
#pragma unroll
    for (int r = 0; r < 4; r++) need = need || (pmax[r] > mrun[r] + 8.0f);
    if (__any(need)) {  // rare: full row-max + rescale
      float tm[4];
#pragma unroll
      for (int r = 0; r < 4; r++) tm[r] = pmax[r];
#pragma unroll
      for (int m = 1; m <= 8; m <<= 1)
#pragma unroll
        for (int r = 0; r < 4; r++) tm[r] = fmaxf(tm[r], __shfl_xor(tm[r], m));
#pragma unroll
      for (int r = 0; r < 4; r++) {
        float mnew = fmaxf(mrun[r], tm[r]);
        float al = __expf(mrun[r] - mnew);
        mrun[r] = mnew;
        lsum[r] *= al;
#pragma unroll
        for (int nt = 0; nt < 4; nt++) acc[nt][r] *= al;
      }
    }
    float p0[4], p1[4];
#pragma unroll
    for (int r = 0; r < 4; r++) {
      p0[r] = __expf(sv0[r] - mrun[r]);
      p1[r] = __expf(sv1[r] - mrun[r]);
      lsum[r] += p0[r] + p1[r];
    }

    __syncthreads();  // previous iter's P/Vt reads complete
    u16* pw = &P[wave][0];
#pragma unroll
    for (int r = 0; r < 4; r++) {
      int prow = quad * 4 + r;
      pw[prow * 40 + lh]      = f2b(p0[r]);
      pw[prow * 40 + 16 + lh] = f2b(p1[r]);
    }
#pragma unroll
    for (int j = 0; j < 8; j++) Vt[(vd0 + j) * 40 + vcc] = vst.u[j];
    __syncthreads();  // P + Vt visible
    bf16x8 ap = *(const bf16x8*)&P[wave][lh * 40 + quad * 8];

#pragma unroll
    for (int nt = 0; nt < 4; nt++) {
      int d = nt * 16 + lh;
      int rc = (quad ^ ((d >> 3) & 3)) << 3;   // read-side key-chunk swizzle
      bf16x8 vb = *(const bf16x8*)&Vt[d * 40 + rc];
      acc[nt] = __builtin_amdgcn_mfma_f32_16x16x32_bf16(ap, vb, acc[nt], 0, 0, 0);
    }
  }

  // one-time row-sum reduction over the 16 lanes of each quad group
#pragma unroll
  for (int m = 1; m <= 8; m <<= 1)
#pragma unroll
    for (int r = 0; r < 4; r++) lsum[r] += __shfl_xor(lsum[r], m);

#pragma unroll
  for (int nt = 0; nt < 4; nt++)
#pragma unroll
    for (int r = 0; r < 4; r++) {
      int qq = q0 + quad * 4 + r;
      if (qq < SEQ) {
        float o = acc[nt][r] / lsum[r];
        obf[((size_t)b * SEQ + qq) * HDIM + head * DHEAD + nt * 16 + lh] = f2b(o);
      }
    }
}

// ---------------- final LN + readout + log_softmax ----------------
__global__ __launch_bounds__(256) void k_readout(const float* __restrict__ h,
    const float* __restrict__ fg, const float* __restrict__ fb,
    const float* __restrict__ outW, const float* __restrict__ outb, float* __restrict__ out) {
  int b = blockIdx.x;
  const float* x = h + (size_t)b * SEQ * HDIM;  // node 0 row
  int t = threadIdx.x;
  float v0 = x[t], v1 = x[t + 256], v2 = x[t + 512];
  float s = v0 + v1 + v2, q = v0*v0 + v1*v1 + v2*v2;
#pragma unroll
  for (int m = 32; m >= 1; m >>= 1) { s += __shfl_xor(s, m); q += __shfl_xor(q, m); }
  __shared__ float ss[4], qq[4];
  int w = t >> 6, lane = t & 63;
  if (lane == 0) { ss[w] = s; qq[w] = q; }
  __syncthreads();
  s = ss[0] + ss[1] + ss[2] + ss[3];
  q = qq[0] + qq[1] + qq[2] + qq[3];
  float mean = s * (1.0f / HDIM);
  float var = q * (1.0f / HDIM) - mean * mean;
  float rs = rsqrtf(var + 1e-5f);
  __shared__ float yn[HDIM];
  yn[t]       = (v0 - mean) * rs * fg[t]       + fb[t];
  yn[t + 256] = (v1 - mean) * rs * fg[t + 256] + fb[t + 256];
  yn[t + 512] = (v2 - mean) * rs * fg[t + 512] + fb[t + 512];
  __syncthreads();
  __shared__ float lg[OUTC];
  for (int j = w; j < OUTC; j += 4) {
    float p = 0.f;
    for (int d = lane; d < HDIM; d += 64) p += yn[d] * outW[(size_t)d * OUTC + j];
#pragma unroll
    for (int m = 32; m >= 1; m >>= 1) p += __shfl_xor(p, m);
    if (lane == 0) lg[j] = p + outb[j];
  }
  __syncthreads();
  if (t == 0) {
    float mx = lg[0];
    for (int j = 1; j < OUTC; j++) mx = fmaxf(mx, lg[j]);
    float se = 0.f;
    for (int j = 0; j < OUTC; j++) se += expf(lg[j] - mx);
    float lse = mx + logf(se);
    for (int j = 0; j < OUTC; j++) out[b * OUTC + j] = lg[j] - lse;
  }
}

extern "C" void kernel_launch(void* const* d_in, const int* in_sizes, int n_in,
                              void* d_out, int out_size, void* d_ws, size_t ws_size,
                              hipStream_t stream) {
  const float* attn_bias = (const float*)d_in[0];
  const float* x      = (const float*)d_in[1];
  const float* enc_W  = (const float*)d_in[2];
  const float* enc_b  = (const float*)d_in[3];
  const float* gtok   = (const float*)d_in[4];
  const float* gvd    = (const float*)d_in[5];
  const float* ln1_g  = (const float*)d_in[6];
  const float* ln1_b  = (const float*)d_in[7];
  const float* Wq     = (const float*)d_in[8];
  const float* bq     = (const float*)d_in[9];
  const float* Wk     = (const float*)d_in[10];
  const float* bk     = (const float*)d_in[11];
  const float* Wv     = (const float*)d_in[12];
  const float* bv     = (const float*)d_in[13];
  const float* Wbias  = (const float*)d_in[14];
  const float* bbias  = (const float*)d_in[15];
  const float* Wo     = (const float*)d_in[16];
  const float* bo     = (const float*)d_in[17];
  const float* ln2_g  = (const float*)d_in[18];
  const float* ln2_b  = (const float*)d_in[19];
  const float* W1     = (const float*)d_in[20];
  const float* b1     = (const float*)d_in[21];
  const float* W2     = (const float*)d_in[22];
  const float* b2     = (const float*)d_in[23];
  const float* fln_g  = (const float*)d_in[24];
  const float* fln_b  = (const float*)d_in[25];
  const float* out_W  = (const float*)d_in[26];
  const float* out_b  = (const float*)d_in[27];
  float* out = (float*)d_out;
  (void)in_sizes; (void)n_in; (void)out_size; (void)ws_size;

  char* ws = (char*)d_ws;
  size_t off = 0;
  auto alloc = [&](size_t bytes) -> char* {
    char* p = ws + off; off += (bytes + 255) & ~(size_t)255; return p;
  };
  u16* wqkvt = (u16*)alloc((size_t)LAYERS * QKVW * HDIM * 2);
  u16* wot   = (u16*)alloc((size_t)LAYERS * HDIM * HDIM * 2);
  u16* w1t   = (u16*)alloc((size_t)LAYERS * FFDIM * HDIM * 2);
  u16* w2t   = (u16*)alloc((size_t)LAYERS * HDIM * FFDIM * 2);
  u16* encwt = (u16*)alloc((size_t)HDIM * INDIM * 2);
  u16* xb    = (u16*)alloc((size_t)MROWS0 * INDIM * 2);
  float* hb  = (float*)alloc((size_t)MROWS * HDIM * 4);
  u16* yb    = (u16*)alloc((size_t)MROWS * HDIM * 2);
  u16* qkvb  = (u16*)alloc((size_t)MROWS * QKVW * 2);
  u16* ob    = (u16*)alloc((size_t)MROWS * HDIM * 2);
  u16* gb8   = (u16*)alloc((size_t)BB * SEQ * SEQ * 8 * 2);
  u16* biasb = (u16*)alloc((size_t)BB * NHEADS * SEQ * SEQ * 2);  // 77 MB, per-layer reuse
  // ffn buffer exactly aliases [qkvb|ob] (7184*2304 + 7184*768 == 7184*3072 bf16),
  // lifetime-disjoint: ffn1 writes after attention/Wo consumed qkv & o.
  u16* ffnb  = qkvb;

  // weights -> bf16 transposed (N,K)
  k_transpose_qkv<<<dim3(24, 24, 18), 256, 0, stream>>>(Wq, Wk, Wv, wqkvt);
  k_transpose_b<<<dim3(24, 24, 6), 256, 0, stream>>>(Wo, wot, HDIM, HDIM);
  k_transpose_b<<<dim3(96, 24, 6), 256, 0, stream>>>(W1, w1t, HDIM, FFDIM);
  k_transpose_b<<<dim3(24, 96, 6), 256, 0, stream>>>(W2, w2t, FFDIM, HDIM);
  k_transpose_b<<<dim3(24, 4, 1), 256, 0, stream>>>(enc_W, encwt, INDIM, HDIM);
  k_cvt<<<dim3((MROWS0 * INDIM) / 256), 256, 0, stream>>>(x, xb, MROWS0 * INDIM);
  k_gb<<<dim3(BB * SEQ), 256, 0, stream>>>(attn_bias, gvd, gb8);

  // grid size helper: NBMp (m-tiles padded to 8) x nbn, 1D
  auto ggrid = [](int M, int nbn) { int nbm = (M + 127) / 128; int nbmp = (nbm + 7) & ~7;
                                    return nbmp * nbn; };

  // node encode + graph token
  k_gemm<<<dim3(ggrid(MROWS0, 6)), 512, 0, stream>>>(xb, encwt, MROWS0, INDIM, 6, 0,
      enc_b, nullptr, nullptr, hb, nullptr);
  k_token<<<dim3(BB), 256, 0, stream>>>(gtok, hb);

  int nbias = (SEQ * SEQ + 255) / 256;
  for (int l = 0; l < LAYERS; l++) {
    k_ln<<<dim3(MROWS), 256, 0, stream>>>(hb, ln1_g + l * HDIM, ln1_b + l * HDIM, yb);
    k_gemm<<<dim3(ggrid(MROWS, 18)), 512, 0, stream>>>(yb, wqkvt + (size_t)l * QKVW * HDIM,
        MROWS, HDIM, 18, 1, bq + l * HDIM, bk + l * HDIM, bv + l * HDIM, nullptr, qkvb);
    k_bias<<<dim3(nbias, BB), 256, 0, stream>>>(gb8, Wbias + l * BDIM * NHEADS,
        bbias + l * NHEADS, biasb);
    k_attn<<<dim3(96, BB), 256, 0, stream>>>(qkvb, biasb, ob);
    k_gemm<<<dim3(ggrid(MROWS, 6)), 512, 0, stream>>>(ob, wot + (size_t)l * HDIM * HDIM,
        MROWS, HDIM, 6, 2, bo + l * HDIM, nullptr, nullptr, hb, nullptr);
    k_ln<<<dim3(MROWS), 256, 0, stream>>>(hb, ln2_g + l * HDIM, ln2_b + l * HDIM, yb);
    k_gemm<<<dim3(ggrid(MROWS, 24)), 512, 0, stream>>>(yb, w1t + (size_t)l * FFDIM * HDIM,
        MROWS, HDIM, 24, 3, b1 + l * FFDIM, nullptr, nullptr, nullptr, ffnb);
    k_gemm<<<dim3(ggrid(MROWS, 6)), 512, 0, stream>>>(ffnb, w2t + (size_t)l * HDIM * FFDIM,
        MROWS, FFDIM, 6, 4, b2 + l * HDIM, nullptr, nullptr, hb, nullptr);
  }
  k_readout<<<dim3(BB), 256, 0, stream>>>(hb, fln_g, fln_b, out_W, out_b, out);
}